// Round 6
// baseline (476.779 us; speedup 1.0000x reference)
//
#include <hip/hip_runtime.h>

typedef __bf16 bf16;
typedef __bf16 bf16x8 __attribute__((ext_vector_type(8)));
typedef float  f32x4  __attribute__((ext_vector_type(4)));

#define L_SEQ 1024
#define DM    1024
#define DI    2048
#define DTR   64
#define DSTATE 16
#define XD    96   // DT_RANK + 2*D_STATE
#define NC    32   // scan chunks
#define CS    32   // steps per chunk

__device__ __forceinline__ float bf2f(bf16 v){ return (float)v; }
__device__ __forceinline__ bf16  f2bf(float v){ return (bf16)v; }

// converted-weights element offsets inside wb
#define OFF_X      0L
#define OFF_INW    1048576L            // [2] x 4194304
#define OFF_XPROJ  9437184L            // [2] x 196608
#define OFF_DTW    9830400L            // [2] x 131072
#define OFF_OUTW   10092544L           // [2] x 2097152
#define OFF_PROJW  14286848L           // 2097152
#define CVT_TOTAL  16384000L

// ---------------------------------------------------------------------------
// fp32 -> bf16 conversion of x + all GEMM weights into wb (16.384M elems)
// ---------------------------------------------------------------------------
__global__ __launch_bounds__(256) void cvt_k(
    const float* __restrict__ x,
    const float* __restrict__ inw0, const float* __restrict__ inw1,
    const float* __restrict__ xp0,  const float* __restrict__ xp1,
    const float* __restrict__ dt0,  const float* __restrict__ dt1,
    const float* __restrict__ ow0,  const float* __restrict__ ow1,
    const float* __restrict__ pw,   bf16* __restrict__ wb)
{
  long i = ((long)blockIdx.x * 256 + threadIdx.x) * 8;
  if (i >= CVT_TOTAL) return;
  const float* src; long off;
  if      (i < OFF_INW)                 { src = x;    off = i - OFF_X; }
  else if (i < OFF_INW + 4194304L)      { src = inw0; off = i - OFF_INW; }
  else if (i < OFF_XPROJ)               { src = inw1; off = i - (OFF_INW + 4194304L); }
  else if (i < OFF_XPROJ + 196608L)     { src = xp0;  off = i - OFF_XPROJ; }
  else if (i < OFF_DTW)                 { src = xp1;  off = i - (OFF_XPROJ + 196608L); }
  else if (i < OFF_DTW + 131072L)       { src = dt0;  off = i - OFF_DTW; }
  else if (i < OFF_OUTW)                { src = dt1;  off = i - (OFF_DTW + 131072L); }
  else if (i < OFF_OUTW + 2097152L)     { src = ow0;  off = i - OFF_OUTW; }
  else if (i < OFF_PROJW)               { src = ow1;  off = i - (OFF_OUTW + 2097152L); }
  else                                  { src = pw;   off = i - OFF_PROJW; }
  f32x4 v0 = *(const f32x4*)(src + off);
  f32x4 v1 = *(const f32x4*)(src + off + 4);
  bf16x8 t;
  #pragma unroll
  for (int q = 0; q < 4; q++) { t[q] = (bf16)v0[q]; t[4+q] = (bf16)v1[q]; }
  *(bf16x8*)(wb + i) = t;
}

// ---------------------------------------------------------------------------
// All-bf16 MFMA GEMM, B^T layout: C[m][n] = sum_k A[m][k] * B[n][k]
// 128x128 tile, BK=64, 256 threads (4 waves, 2x2 of 64x64), 16x16x32 MFMA
// fuseRes=1: epilogue writes fused[row][z*DM+gn] = v + xF[row][gn], bf16,
//   with row = (z ? M-1-gm : gm)  (residual + unflip + concat for out-proj)
// ---------------------------------------------------------------------------
__global__ __launch_bounds__(256) void gemm_bt(
    const bf16* __restrict__ A, const bf16* __restrict__ B0, const bf16* __restrict__ B1,
    void* __restrict__ Cv,
    int M, int N, int K, int lda, int ldb, int ldc,
    long aOffZ, long cOffZ,
    const float* __restrict__ bias0, const float* __restrict__ bias1,
    int flipA1, int writeBf16, int act,
    const float* __restrict__ xF, int fuseRes)
{
  const int tid  = threadIdx.x;
  const int z    = blockIdx.z;
  const bf16*  Bp   = z ? B1 : B0;
  const float* bias = z ? bias1 : bias0;
  const int flip = z ? flipA1 : 0;
  const int bm = blockIdx.x * 128;
  const int bn = blockIdx.y * 128;

  __shared__ bf16 As[128][72];   // +8 pad: frag ds_read_b128 -> 2-way (free)
  __shared__ bf16 Bs[128][72];

  f32x4 acc[4][4];
  f32x4 z4; z4[0]=0.f; z4[1]=0.f; z4[2]=0.f; z4[3]=0.f;
  #pragma unroll
  for (int i=0;i<4;i++)
    #pragma unroll
    for (int j=0;j<4;j++) acc[i][j] = z4;

  const int wave = tid >> 6;
  const int lane = tid & 63;
  const int wm = (wave >> 1) * 64;
  const int wn = (wave & 1) * 64;
  const int fr = lane & 15;
  const int kq = (lane >> 4) * 8;

  const int srow = tid >> 1;
  const int scol = (tid & 1) * 32;

  int ar  = bm + srow;
  int agr = flip ? (M - 1 - ar) : ar;
  const bf16* aBase = A + (long)z * aOffZ + (long)agr * lda + scol;
  int br = bn + srow;
  const bf16* bBase = Bp + (long)br * ldb + scol;
  const bool bOk = (br < N);

  bf16x8 bz;
  #pragma unroll
  for (int q=0;q<8;q++) bz[q] = (bf16)0.f;

  for (int k0 = 0; k0 < K; k0 += 64) {
    bf16x8 a0 = *(const bf16x8*)(aBase + k0);
    bf16x8 a1 = *(const bf16x8*)(aBase + k0 + 8);
    bf16x8 a2 = *(const bf16x8*)(aBase + k0 + 16);
    bf16x8 a3 = *(const bf16x8*)(aBase + k0 + 24);
    bf16x8 b0 = bz, b1 = bz, b2 = bz, b3 = bz;
    if (bOk) {
      b0 = *(const bf16x8*)(bBase + k0);
      b1 = *(const bf16x8*)(bBase + k0 + 8);
      b2 = *(const bf16x8*)(bBase + k0 + 16);
      b3 = *(const bf16x8*)(bBase + k0 + 24);
    }
    *(bf16x8*)&As[srow][scol]      = a0;
    *(bf16x8*)&As[srow][scol + 8]  = a1;
    *(bf16x8*)&As[srow][scol + 16] = a2;
    *(bf16x8*)&As[srow][scol + 24] = a3;
    *(bf16x8*)&Bs[srow][scol]      = b0;
    *(bf16x8*)&Bs[srow][scol + 8]  = b1;
    *(bf16x8*)&Bs[srow][scol + 16] = b2;
    *(bf16x8*)&Bs[srow][scol + 24] = b3;
    __syncthreads();

    #pragma unroll
    for (int ks = 0; ks < 64; ks += 32) {
      bf16x8 af[4], bfr[4];
      #pragma unroll
      for (int i=0;i<4;i++) af[i]  = *(const bf16x8*)&As[wm + i*16 + fr][ks + kq];
      #pragma unroll
      for (int j=0;j<4;j++) bfr[j] = *(const bf16x8*)&Bs[wn + j*16 + fr][ks + kq];
      #pragma unroll
      for (int i=0;i<4;i++)
        #pragma unroll
        for (int j=0;j<4;j++)
          acc[i][j] = __builtin_amdgcn_mfma_f32_16x16x32_bf16(af[i], bfr[j], acc[i][j], 0, 0, 0);
    }
    __syncthreads();
  }

  const int rr = (lane >> 4) * 4;
  const int cc = lane & 15;
  #pragma unroll
  for (int i=0;i<4;i++) {
    #pragma unroll
    for (int j=0;j<4;j++) {
      int gn = bn + wn + j*16 + cc;
      if (gn >= N) continue;
      float bv = bias ? bias[gn] : 0.f;
      #pragma unroll
      for (int r=0;r<4;r++) {
        int gm = bm + wm + i*16 + rr + r;
        float v = acc[i][j][r] + bv;
        if (fuseRes) {
          long row = z ? (long)(M - 1 - gm) : (long)gm;
          float o = v + xF[row * DM + gn];
          ((bf16*)Cv)[row * (2 * DM) + (long)z * DM + gn] = f2bf(o);
        } else {
          if (act == 1) v = (v > 20.f) ? v : log1pf(__expf(v));  // softplus
          long idx = (long)z * cOffZ + (long)gm * ldc + gn;
          if (writeBf16) ((bf16*)Cv)[idx] = f2bf(v);
          else           ((float*)Cv)[idx] = v;
        }
      }
    }
  }
}

// ---------------------------------------------------------------------------
// depthwise causal conv(4) + bias + silu : u[dir][l][d], 8 channels/thread
// ---------------------------------------------------------------------------
__global__ __launch_bounds__(256) void conv_silu_k(
    const bf16* __restrict__ xz, const float* __restrict__ cw0, const float* __restrict__ cw1,
    const float* __restrict__ cb0, const float* __restrict__ cb1, bf16* __restrict__ u)
{
  int gid = blockIdx.x * 256 + threadIdx.x;     // over 2*L*DI/8 = 524288
  int dir = gid >> 18;
  int rem = gid & ((1 << 18) - 1);
  int l = rem >> 8;
  int d0 = (rem & 255) * 8;
  const float* w = dir ? cw1 : cw0;
  const float* b = dir ? cb1 : cb0;
  const bf16* xzd = xz + (long)dir * L_SEQ * (2 * DI);
  float acc[8];
  #pragma unroll
  for (int q = 0; q < 8; q++) acc[q] = b[d0 + q];
  #pragma unroll
  for (int j = 0; j < 4; j++) {
    int ll = l - 3 + j;
    if (ll < 0) continue;
    bf16x8 xv = *(const bf16x8*)(xzd + (long)ll * (2 * DI) + d0);
    #pragma unroll
    for (int q = 0; q < 8; q++) acc[q] += w[(d0 + q) * 4 + j] * bf2f(xv[q]);
  }
  bf16x8 o;
  #pragma unroll
  for (int q = 0; q < 8; q++) {
    float s = acc[q] / (1.f + __expf(-acc[q]));
    o[q] = f2bf(s);
  }
  *(bf16x8*)(u + (long)dir * L_SEQ * DI + (long)l * DI + d0) = o;
}

// ---------------------------------------------------------------------------
// Chunk-parallel selective scan, 2 kernels, no grid sync (XCD-coherence safe):
// p1: per (dir,chunk,d) local scan from h=0 -> S_c = hout (bf16), sumd (f32)
// p23: per (dir,chunk,d): recompute prefix h_start = sum_{c'<c} decays*S_{c'}
//      (<=31 steps, redundant but cheap), then rescan chunk with gating -> g
// ---------------------------------------------------------------------------
__global__ __launch_bounds__(256) void scan_p1(
    const bf16* __restrict__ xz, const bf16* __restrict__ u, const bf16* __restrict__ xdbl,
    const float* __restrict__ Alog0, const float* __restrict__ Alog1,
    bf16* __restrict__ hout, float* __restrict__ sumd)
{
  const int tid = threadIdx.x;
  const int c   = blockIdx.y;
  const int dir = blockIdx.z;
  const int d   = blockIdx.x * 256 + tid;
  const float* Alog = dir ? Alog1 : Alog0;
  const bf16* dl = xz + (long)dir * L_SEQ * (2 * DI);       // delta in xi cols
  const bf16* ud = u  + (long)dir * L_SEQ * DI;
  const bf16* xd = xdbl + (long)dir * L_SEQ * XD;
  const int l0 = c * CS;

  __shared__ float lb[CS][16];
  {
    int i = tid * 2;
    int ll = i >> 4, n = i & 15;
    const bf16* p = xd + (long)(l0 + ll) * XD + DTR + n;
    lb[ll][n]     = bf2f(p[0]);
    lb[ll][n + 1] = bf2f(p[1]);
  }
  __syncthreads();

  float An[16], h[16];
  #pragma unroll
  for (int n = 0; n < 16; n++) { An[n] = -__expf(Alog[d * 16 + n]); h[n] = 0.f; }
  float sd = 0.f;

  #pragma unroll 4
  for (int ll = 0; ll < CS; ll++) {
    int l = l0 + ll;
    float dlt = bf2f(dl[(long)l * (2 * DI) + d]);
    float uu  = bf2f(ud[(long)l * DI + d]);
    sd += dlt;
    float du = dlt * uu;
    #pragma unroll
    for (int n = 0; n < 16; n++) {
      float a = __expf(dlt * An[n]);
      h[n] = h[n] * a + du * lb[ll][n];
    }
  }

  bf16* hp = hout + (((long)dir * NC + c) * DI + d) * 16;
  bf16x8 o0, o1;
  #pragma unroll
  for (int n = 0; n < 8; n++) { o0[n] = f2bf(h[n]); o1[n] = f2bf(h[8 + n]); }
  *(bf16x8*)hp = o0;
  *(bf16x8*)(hp + 8) = o1;
  sumd[((long)dir * NC + c) * DI + d] = sd;
}

__global__ __launch_bounds__(256) void scan_p23(
    const bf16* xz, const bf16* u, const bf16* __restrict__ xdbl,
    const float* __restrict__ Alog0, const float* __restrict__ Alog1,
    const float* __restrict__ Dp0, const float* __restrict__ Dp1,
    const bf16* __restrict__ hout, const float* __restrict__ sumd, bf16* g)
{
  const int tid = threadIdx.x;
  const int c   = blockIdx.y;
  const int dir = blockIdx.z;
  const int d   = blockIdx.x * 256 + tid;
  const float* Alog = dir ? Alog1 : Alog0;
  const float* Dp   = dir ? Dp1 : Dp0;
  const bf16* row0 = xz + (long)dir * L_SEQ * (2 * DI);   // delta @ +d, z @ +DI+d
  const bf16* ud   = u  + (long)dir * L_SEQ * DI;
  const bf16* xd   = xdbl + (long)dir * L_SEQ * XD;
  bf16* gd = g + (long)dir * L_SEQ * DI;
  const int l0 = c * CS;

  __shared__ float lb[CS][16];
  __shared__ float lc[CS][16];
  {
    int i = tid * 4;
    int ll = i >> 5, j = i & 31;
    const bf16* p = xd + (long)(l0 + ll) * XD + DTR + j;
    #pragma unroll
    for (int q = 0; q < 4; q++) {
      int jj = j + q;
      float v = bf2f(p[q]);
      if (jj < 16) lb[ll][jj] = v; else lc[ll][jj - 16] = v;
    }
  }
  __syncthreads();

  float An[16], h[16];
  #pragma unroll
  for (int n = 0; n < 16; n++) {
    An[n] = -__expf(Alog[d * 16 + n]);
    h[n] = 0.f;
  }

  // prefix combine: h_start for chunk c (redundant per-chunk recompute)
  for (int cp = 0; cp < c; cp++) {
    long base = ((long)dir * NC + cp) * DI + d;
    float sd = sumd[base];
    const bf16* hp = hout + base * 16;
    bf16x8 s0 = *(const bf16x8*)hp;
    bf16x8 s1 = *(const bf16x8*)(hp + 8);
    #pragma unroll
    for (int n = 0; n < 16; n++) {
      float P = __expf(An[n] * sd);
      float S = bf2f(n < 8 ? s0[n & 7] : s1[n & 7]);
      h[n] = P * h[n] + S;
    }
  }

  const float Dpv = Dp[d];
  #pragma unroll 4
  for (int ll = 0; ll < CS; ll++) {
    int l = l0 + ll;
    float dlt = bf2f(row0[(long)l * (2 * DI) + d]);
    float zv  = bf2f(row0[(long)l * (2 * DI) + DI + d]);
    float uu  = bf2f(ud[(long)l * DI + d]);
    float du = dlt * uu;
    float y = 0.f;
    #pragma unroll
    for (int n = 0; n < 16; n++) {
      float a = __expf(dlt * An[n]);
      h[n] = h[n] * a + du * lb[ll][n];
      y += h[n] * lc[ll][n];
    }
    y += uu * Dpv;
    float sz = zv / (1.f + __expf(-zv));
    gd[(long)l * DI + d] = f2bf(y * sz);
  }
}

// ---------------------------------------------------------------------------
// +proj_b then LayerNorm over last dim (1024), write fp32 out
// ---------------------------------------------------------------------------
__global__ __launch_bounds__(256) void ln_k(
    const float* __restrict__ fin, const float* __restrict__ pb,
    const float* __restrict__ lnw, const float* __restrict__ lnb, float* __restrict__ out)
{
  int row = blockIdx.x;
  int tid = threadIdx.x;
  float v[4]; float s1 = 0.f, s2 = 0.f;
  #pragma unroll
  for (int j = 0; j < 4; j++) {
    int c = tid + j * 256;
    v[j] = fin[(long)row * DM + c] + pb[c];
    s1 += v[j]; s2 += v[j] * v[j];
  }
  #pragma unroll
  for (int off = 32; off; off >>= 1) { s1 += __shfl_down(s1, off); s2 += __shfl_down(s2, off); }
  __shared__ float red[8];
  int wave = tid >> 6, lane = tid & 63;
  if (lane == 0) { red[wave] = s1; red[4 + wave] = s2; }
  __syncthreads();
  float t1 = red[0] + red[1] + red[2] + red[3];
  float t2 = red[4] + red[5] + red[6] + red[7];
  float mu = t1 / DM;
  float var = t2 / DM - mu * mu;
  float inv = rsqrtf(var + 1e-5f);
  #pragma unroll
  for (int j = 0; j < 4; j++) {
    int c = tid + j * 256;
    out[(long)row * DM + c] = (v[j] - mu) * inv * lnw[c] + lnb[c];
  }
}

// ---------------------------------------------------------------------------
extern "C" void kernel_launch(void* const* d_in, const int* in_sizes, int n_in,
                              void* d_out, int out_size, void* d_ws, size_t ws_size,
                              hipStream_t stream)
{
  const float* x         = (const float*)d_in[0];
  const float* fw_conv_w = (const float*)d_in[2];
  const float* fw_conv_b = (const float*)d_in[3];
  const float* fw_dt_b   = (const float*)d_in[6];
  const float* fw_Alog   = (const float*)d_in[7];
  const float* fw_Dp     = (const float*)d_in[8];
  const float* bw_conv_w = (const float*)d_in[11];
  const float* bw_conv_b = (const float*)d_in[12];
  const float* bw_dt_b   = (const float*)d_in[15];
  const float* bw_Alog   = (const float*)d_in[16];
  const float* bw_Dp     = (const float*)d_in[17];
  const float* proj_b    = (const float*)d_in[20];
  const float* ln_w      = (const float*)d_in[21];
  const float* ln_b      = (const float*)d_in[22];

  // workspace layout (peak ~62.3 MB):
  //   xz bf16 [2][1024][4096]  @ 0..16MB  (delta overwrites xi cols; dead after scan)
  //   u/g bf16 [2][1024][2048] @ 16..24MB (g in-place over u)
  //   xdbl bf16 [2][1024][96]  @ 24..24.4MB
  //   sumd f32 [2][32][2048]   @ 25..25.5MB
  //   hout bf16 [2][32][2048][16] @ 26..30MB
  //   wb bf16 (converted x + weights) @ 30..61.3MB
  //   phase 2 (over dead xz): fused bf16 [1024][2048] @0..4MB, fin f32 @4..8MB
  char* ws = (char*)d_ws;
  const size_t MB = 1024 * 1024;
  bf16*  xz    = (bf16*)(ws + 0);
  bf16*  u     = (bf16*)(ws + 16 * MB);
  bf16*  xdbl  = (bf16*)(ws + 24 * MB);
  float* sumd  = (float*)(ws + 25 * MB);
  bf16*  hout  = (bf16*)(ws + 26 * MB);
  bf16*  wb    = (bf16*)(ws + 30 * MB);
  bf16*  g     = u;
  bf16*  delta = xz;                      // xi columns, stride 4096
  bf16*  fused = (bf16*)(ws + 0);
  float* fin   = (float*)(ws + 4 * MB);

  bf16* xb     = wb + OFF_X;
  bf16* inw    = wb + OFF_INW;     // [2][4096][1024]
  bf16* xprojw = wb + OFF_XPROJ;   // [2][96][2048]
  bf16* dtw    = wb + OFF_DTW;     // [2][2048][64]
  bf16* outw   = wb + OFF_OUTW;    // [2][1024][2048]
  bf16* projw  = wb + OFF_PROJW;   // [1024][2048]

  dim3 blk(256);

  // 0. convert x + weights to bf16
  cvt_k<<<(CVT_TOTAL / 8 + 255) / 256, blk, 0, stream>>>(
      x, (const float*)d_in[1], (const float*)d_in[10],
      (const float*)d_in[4], (const float*)d_in[13],
      (const float*)d_in[5], (const float*)d_in[14],
      (const float*)d_in[9], (const float*)d_in[18],
      (const float*)d_in[19], wb);

  // 1. in-proj: xz[dir] = (flip?)xb @ in_w^T   (M=1024, N=4096, K=1024)
  gemm_bt<<<dim3(8, 32, 2), blk, 0, stream>>>(
      xb, inw, inw + 4194304L, (void*)xz, 1024, 4096, 1024, 1024, 1024, 4096,
      0L, (long)1024 * 4096, nullptr, nullptr, 1, 1, 0, nullptr, 0);

  // 2. depthwise conv + silu -> u
  conv_silu_k<<<2048, blk, 0, stream>>>(xz, fw_conv_w, bw_conv_w, fw_conv_b, bw_conv_b, u);

  // 3. x_dbl = u @ xproj_w^T   (N=96)
  gemm_bt<<<dim3(8, 1, 2), blk, 0, stream>>>(
      u, xprojw, xprojw + 196608L, (void*)xdbl, 1024, 96, 2048, 2048, 2048, 96,
      (long)1024 * 2048, (long)1024 * 96, nullptr, nullptr, 0, 1, 0, nullptr, 0);

  // 4. delta = softplus(dt @ dt_w^T + dt_b) -> xi cols of xz (ldc=4096)
  gemm_bt<<<dim3(8, 16, 2), blk, 0, stream>>>(
      xdbl, dtw, dtw + 131072L, (void*)delta, 1024, 2048, 64, 96, 64, 4096,
      (long)1024 * 96, (long)1024 * 4096, fw_dt_b, bw_dt_b, 0, 1, 1, nullptr, 0);

  // 5. chunk-parallel scan (2 kernels, coherence via launch boundaries)
  scan_p1<<<dim3(8, NC, 2), blk, 0, stream>>>(xz, u, xdbl, fw_Alog, bw_Alog, hout, sumd);
  scan_p23<<<dim3(8, NC, 2), blk, 0, stream>>>(xz, u, xdbl, fw_Alog, bw_Alog,
                                               fw_Dp, bw_Dp, hout, sumd, g);

  // 6. out-proj + residual + unflip + concat -> fused (bf16 [1024][2048])
  gemm_bt<<<dim3(8, 8, 2), blk, 0, stream>>>(
      g, outw, outw + 2097152L, (void*)fused, 1024, 1024, 2048, 2048, 2048, 1024,
      (long)1024 * 2048, 0L, nullptr, nullptr, 0, 1, 0, x, 1);

  // 7. final proj: fin = fused @ proj_w^T (fp32 out)
  gemm_bt<<<dim3(8, 8, 1), blk, 0, stream>>>(
      fused, projw, projw, (void*)fin, 1024, 1024, 2048, 2048, 2048, 1024,
      0L, 0L, nullptr, nullptr, 0, 0, 0, nullptr, 0);

  // 8. +proj_b, LayerNorm -> d_out (fp32)
  ln_k<<<1024, blk, 0, stream>>>(fin, proj_b, ln_w, ln_b, (float*)d_out);
}

// Round 7
// 463.777 us; speedup vs baseline: 1.0280x; 1.0280x over previous
//
#include <hip/hip_runtime.h>

typedef __bf16 bf16;
typedef __bf16 bf16x8 __attribute__((ext_vector_type(8)));
typedef float  f32x4  __attribute__((ext_vector_type(4)));

#define L_SEQ 1024
#define DM    1024
#define DI    2048
#define DTR   64
#define DSTATE 16
#define XD    96   // DT_RANK + 2*D_STATE
#define NC    32   // scan chunks
#define CS    32   // steps per chunk

__device__ __forceinline__ float bf2f(bf16 v){ return (float)v; }
__device__ __forceinline__ bf16  f2bf(float v){ return (bf16)v; }

// async global->LDS, 16B per lane; LDS dest = wave-uniform base + lane*16
__device__ __forceinline__ void gl_lds16(const bf16* g, bf16* l) {
  __builtin_amdgcn_global_load_lds(
      (const __attribute__((address_space(1))) unsigned int*)g,
      (__attribute__((address_space(3))) unsigned int*)l, 16, 0, 0);
}

// converted-weights element offsets inside wb
#define OFF_X      0L
#define OFF_INW    1048576L            // [2] x 4194304
#define OFF_XPROJ  9437184L            // [2] x 196608
#define OFF_DTW    9830400L            // [2] x 131072
#define OFF_OUTW   10092544L           // [2] x 2097152
#define OFF_PROJW  14286848L           // 2097152
#define CVT_TOTAL  16384000L

// ---------------------------------------------------------------------------
// fp32 -> bf16 conversion of x + all GEMM weights into wb (16.384M elems)
// ---------------------------------------------------------------------------
__global__ __launch_bounds__(256) void cvt_k(
    const float* __restrict__ x,
    const float* __restrict__ inw0, const float* __restrict__ inw1,
    const float* __restrict__ xp0,  const float* __restrict__ xp1,
    const float* __restrict__ dt0,  const float* __restrict__ dt1,
    const float* __restrict__ ow0,  const float* __restrict__ ow1,
    const float* __restrict__ pw,   bf16* __restrict__ wb)
{
  long i = ((long)blockIdx.x * 256 + threadIdx.x) * 8;
  if (i >= CVT_TOTAL) return;
  const float* src; long off;
  if      (i < OFF_INW)                 { src = x;    off = i - OFF_X; }
  else if (i < OFF_INW + 4194304L)      { src = inw0; off = i - OFF_INW; }
  else if (i < OFF_XPROJ)               { src = inw1; off = i - (OFF_INW + 4194304L); }
  else if (i < OFF_XPROJ + 196608L)     { src = xp0;  off = i - OFF_XPROJ; }
  else if (i < OFF_DTW)                 { src = xp1;  off = i - (OFF_XPROJ + 196608L); }
  else if (i < OFF_DTW + 131072L)       { src = dt0;  off = i - OFF_DTW; }
  else if (i < OFF_OUTW)                { src = dt1;  off = i - (OFF_DTW + 131072L); }
  else if (i < OFF_OUTW + 2097152L)     { src = ow0;  off = i - OFF_OUTW; }
  else if (i < OFF_PROJW)               { src = ow1;  off = i - (OFF_OUTW + 2097152L); }
  else                                  { src = pw;   off = i - OFF_PROJW; }
  f32x4 v0 = *(const f32x4*)(src + off);
  f32x4 v1 = *(const f32x4*)(src + off + 4);
  bf16x8 t;
  #pragma unroll
  for (int q = 0; q < 4; q++) { t[q] = (bf16)v0[q]; t[4+q] = (bf16)v1[q]; }
  *(bf16x8*)(wb + i) = t;
}

// ---------------------------------------------------------------------------
// All-bf16 MFMA GEMM, B^T layout: C[m][n] = sum_k A[m][k] * B[n][k]
// 128x128 tile, BK=64, 256 threads (4 waves, 2x2 of 64x64), 16x16x32 MFMA.
// Staging via global_load_lds (16B/lane) into UNPADDED LDS with XOR-8 chunk
// swizzle: LDS chunk (r,j) holds global chunk (r, j^(r&7)); fragment read of
// global chunk (R,q) -> LDS slot R*8 + (q^(R&7)). Bank spread = conflict-free.
// fuseRes=1: epilogue writes fused[row][z*DM+gn] = v + xF[row][gn], bf16,
//   with row = (z ? M-1-gm : gm)  (residual + unflip + concat for out-proj)
// ---------------------------------------------------------------------------
__global__ __launch_bounds__(256) void gemm_bt(
    const bf16* __restrict__ A, const bf16* __restrict__ B0, const bf16* __restrict__ B1,
    void* __restrict__ Cv,
    int M, int N, int K, int lda, int ldb, int ldc,
    long aOffZ, long cOffZ,
    const float* __restrict__ bias0, const float* __restrict__ bias1,
    int flipA1, int writeBf16, int act,
    const float* __restrict__ xF, int fuseRes)
{
  const int tid  = threadIdx.x;
  const int z    = blockIdx.z;
  const bf16*  Bp   = z ? B1 : B0;
  const float* bias = z ? bias1 : bias0;
  const int flip = z ? flipA1 : 0;
  const int bm = blockIdx.x * 128;
  const int bn = blockIdx.y * 128;

  __shared__ bf16 As[128 * 64];   // unpadded (global_load_lds requirement)
  __shared__ bf16 Bs[128 * 64];

  f32x4 acc[4][4];
  f32x4 z4; z4[0]=0.f; z4[1]=0.f; z4[2]=0.f; z4[3]=0.f;
  #pragma unroll
  for (int i=0;i<4;i++)
    #pragma unroll
    for (int j=0;j<4;j++) acc[i][j] = z4;

  const int wave = tid >> 6;
  const int lane = tid & 63;
  const int wm = (wave >> 1) * 64;
  const int wn = (wave & 1) * 64;
  const int fr  = lane & 15;         // fragment row
  const int frx = fr & 7;            // xor key for frag reads
  const int kqc = lane >> 4;         // quad chunk (0..3)

  // staging source addresses: 4 calls/wave per tile, call t covers chunks
  // c = (wave*4+t)*64 + lane ; r = c>>3 ; j = (c&7)^(r&7)
  const bf16* aSrc[4];
  const bf16* bSrc[4];
  int ldsOff[4];
  #pragma unroll
  for (int t = 0; t < 4; t++) {
    int c = wave * 256 + t * 64 + lane;
    int r = c >> 3;
    int j = (c & 7) ^ (r & 7);
    int ar = bm + r;
    int agr = flip ? (M - 1 - ar) : ar;
    aSrc[t] = A + (long)z * aOffZ + (long)agr * lda + j * 8;
    int br = bn + r; if (br > N - 1) br = N - 1;   // clamp (cols skipped later)
    bSrc[t] = Bp + (long)br * ldb + j * 8;
    ldsOff[t] = (wave * 4 + t) * 512;              // 512 bf16 = 1KB per call
  }

  for (int k0 = 0; k0 < K; k0 += 64) {
    #pragma unroll
    for (int t = 0; t < 4; t++) gl_lds16(aSrc[t] + k0, &As[ldsOff[t]]);
    #pragma unroll
    for (int t = 0; t < 4; t++) gl_lds16(bSrc[t] + k0, &Bs[ldsOff[t]]);
    __syncthreads();

    #pragma unroll
    for (int ks8 = 0; ks8 < 8; ks8 += 4) {   // chunk-base 0, 4 (= k 0, 32)
      bf16x8 af[4], bfr[4];
      #pragma unroll
      for (int i=0;i<4;i++) {
        int row = wm + i*16 + fr;
        af[i]  = *(const bf16x8*)&As[(row * 8 + ((ks8 + kqc) ^ frx)) * 8];
      }
      #pragma unroll
      for (int j=0;j<4;j++) {
        int row = wn + j*16 + fr;
        bfr[j] = *(const bf16x8*)&Bs[(row * 8 + ((ks8 + kqc) ^ frx)) * 8];
      }
      #pragma unroll
      for (int i=0;i<4;i++)
        #pragma unroll
        for (int j=0;j<4;j++)
          acc[i][j] = __builtin_amdgcn_mfma_f32_16x16x32_bf16(af[i], bfr[j], acc[i][j], 0, 0, 0);
    }
    __syncthreads();
  }

  const int rr = (lane >> 4) * 4;
  const int cc = lane & 15;
  #pragma unroll
  for (int i=0;i<4;i++) {
    #pragma unroll
    for (int j=0;j<4;j++) {
      int gn = bn + wn + j*16 + cc;
      if (gn >= N) continue;
      float bv = bias ? bias[gn] : 0.f;
      #pragma unroll
      for (int r=0;r<4;r++) {
        int gm = bm + wm + i*16 + rr + r;
        float v = acc[i][j][r] + bv;
        if (fuseRes) {
          long row = z ? (long)(M - 1 - gm) : (long)gm;
          float o = v + xF[row * DM + gn];
          ((bf16*)Cv)[row * (2 * DM) + (long)z * DM + gn] = f2bf(o);
        } else {
          if (act == 1) v = (v > 20.f) ? v : log1pf(__expf(v));  // softplus
          long idx = (long)z * cOffZ + (long)gm * ldc + gn;
          if (writeBf16) ((bf16*)Cv)[idx] = f2bf(v);
          else           ((float*)Cv)[idx] = v;
        }
      }
    }
  }
}

// ---------------------------------------------------------------------------
// depthwise causal conv(4) + bias + silu : u[dir][l][d], 8 channels/thread
// ---------------------------------------------------------------------------
__global__ __launch_bounds__(256) void conv_silu_k(
    const bf16* __restrict__ xz, const float* __restrict__ cw0, const float* __restrict__ cw1,
    const float* __restrict__ cb0, const float* __restrict__ cb1, bf16* __restrict__ u)
{
  int gid = blockIdx.x * 256 + threadIdx.x;     // over 2*L*DI/8 = 524288
  int dir = gid >> 18;
  int rem = gid & ((1 << 18) - 1);
  int l = rem >> 8;
  int d0 = (rem & 255) * 8;
  const float* w = dir ? cw1 : cw0;
  const float* b = dir ? cb1 : cb0;
  const bf16* xzd = xz + (long)dir * L_SEQ * (2 * DI);
  float acc[8];
  #pragma unroll
  for (int q = 0; q < 8; q++) acc[q] = b[d0 + q];
  #pragma unroll
  for (int j = 0; j < 4; j++) {
    int ll = l - 3 + j;
    if (ll < 0) continue;
    bf16x8 xv = *(const bf16x8*)(xzd + (long)ll * (2 * DI) + d0);
    #pragma unroll
    for (int q = 0; q < 8; q++) acc[q] += w[(d0 + q) * 4 + j] * bf2f(xv[q]);
  }
  bf16x8 o;
  #pragma unroll
  for (int q = 0; q < 8; q++) {
    float s = acc[q] / (1.f + __expf(-acc[q]));
    o[q] = f2bf(s);
  }
  *(bf16x8*)(u + (long)dir * L_SEQ * DI + (long)l * DI + d0) = o;
}

// ---------------------------------------------------------------------------
// Chunk-parallel selective scan, 2 kernels, no grid sync (XCD-coherence safe)
// ---------------------------------------------------------------------------
__global__ __launch_bounds__(256) void scan_p1(
    const bf16* __restrict__ xz, const bf16* __restrict__ u, const bf16* __restrict__ xdbl,
    const float* __restrict__ Alog0, const float* __restrict__ Alog1,
    bf16* __restrict__ hout, float* __restrict__ sumd)
{
  const int tid = threadIdx.x;
  const int c   = blockIdx.y;
  const int dir = blockIdx.z;
  const int d   = blockIdx.x * 256 + tid;
  const float* Alog = dir ? Alog1 : Alog0;
  const bf16* dl = xz + (long)dir * L_SEQ * (2 * DI);       // delta in xi cols
  const bf16* ud = u  + (long)dir * L_SEQ * DI;
  const bf16* xd = xdbl + (long)dir * L_SEQ * XD;
  const int l0 = c * CS;

  __shared__ float lb[CS][16];
  {
    int i = tid * 2;
    int ll = i >> 4, n = i & 15;
    const bf16* p = xd + (long)(l0 + ll) * XD + DTR + n;
    lb[ll][n]     = bf2f(p[0]);
    lb[ll][n + 1] = bf2f(p[1]);
  }
  __syncthreads();

  float An[16], h[16];
  #pragma unroll
  for (int n = 0; n < 16; n++) { An[n] = -__expf(Alog[d * 16 + n]); h[n] = 0.f; }
  float sd = 0.f;

  #pragma unroll 4
  for (int ll = 0; ll < CS; ll++) {
    int l = l0 + ll;
    float dlt = bf2f(dl[(long)l * (2 * DI) + d]);
    float uu  = bf2f(ud[(long)l * DI + d]);
    sd += dlt;
    float du = dlt * uu;
    #pragma unroll
    for (int n = 0; n < 16; n++) {
      float a = __expf(dlt * An[n]);
      h[n] = h[n] * a + du * lb[ll][n];
    }
  }

  bf16* hp = hout + (((long)dir * NC + c) * DI + d) * 16;
  bf16x8 o0, o1;
  #pragma unroll
  for (int n = 0; n < 8; n++) { o0[n] = f2bf(h[n]); o1[n] = f2bf(h[8 + n]); }
  *(bf16x8*)hp = o0;
  *(bf16x8*)(hp + 8) = o1;
  sumd[((long)dir * NC + c) * DI + d] = sd;
}

__global__ __launch_bounds__(256) void scan_p23(
    const bf16* xz, const bf16* u, const bf16* __restrict__ xdbl,
    const float* __restrict__ Alog0, const float* __restrict__ Alog1,
    const float* __restrict__ Dp0, const float* __restrict__ Dp1,
    const bf16* __restrict__ hout, const float* __restrict__ sumd, bf16* g)
{
  const int tid = threadIdx.x;
  const int c   = blockIdx.y;
  const int dir = blockIdx.z;
  const int d   = blockIdx.x * 256 + tid;
  const float* Alog = dir ? Alog1 : Alog0;
  const float* Dp   = dir ? Dp1 : Dp0;
  const bf16* row0 = xz + (long)dir * L_SEQ * (2 * DI);   // delta @ +d, z @ +DI+d
  const bf16* ud   = u  + (long)dir * L_SEQ * DI;
  const bf16* xd   = xdbl + (long)dir * L_SEQ * XD;
  bf16* gd = g + (long)dir * L_SEQ * DI;
  const int l0 = c * CS;

  __shared__ float lb[CS][16];
  __shared__ float lc[CS][16];
  {
    int i = tid * 4;
    int ll = i >> 5, j = i & 31;
    const bf16* p = xd + (long)(l0 + ll) * XD + DTR + j;
    #pragma unroll
    for (int q = 0; q < 4; q++) {
      int jj = j + q;
      float v = bf2f(p[q]);
      if (jj < 16) lb[ll][jj] = v; else lc[ll][jj - 16] = v;
    }
  }
  __syncthreads();

  float An[16], h[16];
  #pragma unroll
  for (int n = 0; n < 16; n++) {
    An[n] = -__expf(Alog[d * 16 + n]);
    h[n] = 0.f;
  }

  // prefix combine: h_start for chunk c (redundant per-chunk recompute)
  for (int cp = 0; cp < c; cp++) {
    long base = ((long)dir * NC + cp) * DI + d;
    float sd = sumd[base];
    const bf16* hp = hout + base * 16;
    bf16x8 s0 = *(const bf16x8*)hp;
    bf16x8 s1 = *(const bf16x8*)(hp + 8);
    #pragma unroll
    for (int n = 0; n < 16; n++) {
      float P = __expf(An[n] * sd);
      float S = bf2f(n < 8 ? s0[n & 7] : s1[n & 7]);
      h[n] = P * h[n] + S;
    }
  }

  const float Dpv = Dp[d];
  #pragma unroll 4
  for (int ll = 0; ll < CS; ll++) {
    int l = l0 + ll;
    float dlt = bf2f(row0[(long)l * (2 * DI) + d]);
    float zv  = bf2f(row0[(long)l * (2 * DI) + DI + d]);
    float uu  = bf2f(ud[(long)l * DI + d]);
    float du = dlt * uu;
    float y = 0.f;
    #pragma unroll
    for (int n = 0; n < 16; n++) {
      float a = __expf(dlt * An[n]);
      h[n] = h[n] * a + du * lb[ll][n];
      y += h[n] * lc[ll][n];
    }
    y += uu * Dpv;
    float sz = zv / (1.f + __expf(-zv));
    gd[(long)l * DI + d] = f2bf(y * sz);
  }
}

// ---------------------------------------------------------------------------
// +proj_b then LayerNorm over last dim (1024), write fp32 out
// ---------------------------------------------------------------------------
__global__ __launch_bounds__(256) void ln_k(
    const float* __restrict__ fin, const float* __restrict__ pb,
    const float* __restrict__ lnw, const float* __restrict__ lnb, float* __restrict__ out)
{
  int row = blockIdx.x;
  int tid = threadIdx.x;
  float v[4]; float s1 = 0.f, s2 = 0.f;
  #pragma unroll
  for (int j = 0; j < 4; j++) {
    int c = tid + j * 256;
    v[j] = fin[(long)row * DM + c] + pb[c];
    s1 += v[j]; s2 += v[j] * v[j];
  }
  #pragma unroll
  for (int off = 32; off; off >>= 1) { s1 += __shfl_down(s1, off); s2 += __shfl_down(s2, off); }
  __shared__ float red[8];
  int wave = tid >> 6, lane = tid & 63;
  if (lane == 0) { red[wave] = s1; red[4 + wave] = s2; }
  __syncthreads();
  float t1 = red[0] + red[1] + red[2] + red[3];
  float t2 = red[4] + red[5] + red[6] + red[7];
  float mu = t1 / DM;
  float var = t2 / DM - mu * mu;
  float inv = rsqrtf(var + 1e-5f);
  #pragma unroll
  for (int j = 0; j < 4; j++) {
    int c = tid + j * 256;
    out[(long)row * DM + c] = (v[j] - mu) * inv * lnw[c] + lnb[c];
  }
}

// ---------------------------------------------------------------------------
extern "C" void kernel_launch(void* const* d_in, const int* in_sizes, int n_in,
                              void* d_out, int out_size, void* d_ws, size_t ws_size,
                              hipStream_t stream)
{
  const float* x         = (const float*)d_in[0];
  const float* fw_conv_w = (const float*)d_in[2];
  const float* fw_conv_b = (const float*)d_in[3];
  const float* fw_dt_b   = (const float*)d_in[6];
  const float* fw_Alog   = (const float*)d_in[7];
  const float* fw_Dp     = (const float*)d_in[8];
  const float* bw_conv_w = (const float*)d_in[11];
  const float* bw_conv_b = (const float*)d_in[12];
  const float* bw_dt_b   = (const float*)d_in[15];
  const float* bw_Alog   = (const float*)d_in[16];
  const float* bw_Dp     = (const float*)d_in[17];
  const float* proj_b    = (const float*)d_in[20];
  const float* ln_w      = (const float*)d_in[21];
  const float* ln_b      = (const float*)d_in[22];

  // workspace layout (peak ~62.3 MB):
  //   xz bf16 [2][1024][4096]  @ 0..16MB  (delta overwrites xi cols; dead after scan)
  //   u/g bf16 [2][1024][2048] @ 16..24MB (g in-place over u)
  //   xdbl bf16 [2][1024][96]  @ 24..24.4MB
  //   sumd f32 [2][32][2048]   @ 25..25.5MB
  //   hout bf16 [2][32][2048][16] @ 26..30MB
  //   wb bf16 (converted x + weights) @ 30..61.3MB
  //   phase 2 (over dead xz): fused bf16 [1024][2048] @0..4MB, fin f32 @4..8MB
  char* ws = (char*)d_ws;
  const size_t MB = 1024 * 1024;
  bf16*  xz    = (bf16*)(ws + 0);
  bf16*  u     = (bf16*)(ws + 16 * MB);
  bf16*  xdbl  = (bf16*)(ws + 24 * MB);
  float* sumd  = (float*)(ws + 25 * MB);
  bf16*  hout  = (bf16*)(ws + 26 * MB);
  bf16*  wb    = (bf16*)(ws + 30 * MB);
  bf16*  g     = u;
  bf16*  delta = xz;                      // xi columns, stride 4096
  bf16*  fused = (bf16*)(ws + 0);
  float* fin   = (float*)(ws + 4 * MB);

  bf16* xb     = wb + OFF_X;
  bf16* inw    = wb + OFF_INW;     // [2][4096][1024]
  bf16* xprojw = wb + OFF_XPROJ;   // [2][96][2048]
  bf16* dtw    = wb + OFF_DTW;     // [2][2048][64]
  bf16* outw   = wb + OFF_OUTW;    // [2][1024][2048]
  bf16* projw  = wb + OFF_PROJW;   // [1024][2048]

  dim3 blk(256);

  // 0. convert x + weights to bf16
  cvt_k<<<(CVT_TOTAL / 8 + 255) / 256, blk, 0, stream>>>(
      x, (const float*)d_in[1], (const float*)d_in[10],
      (const float*)d_in[4], (const float*)d_in[13],
      (const float*)d_in[5], (const float*)d_in[14],
      (const float*)d_in[9], (const float*)d_in[18],
      (const float*)d_in[19], wb);

  // 1. in-proj: xz[dir] = (flip?)xb @ in_w^T   (M=1024, N=4096, K=1024)
  gemm_bt<<<dim3(8, 32, 2), blk, 0, stream>>>(
      xb, inw, inw + 4194304L, (void*)xz, 1024, 4096, 1024, 1024, 1024, 4096,
      0L, (long)1024 * 4096, nullptr, nullptr, 1, 1, 0, nullptr, 0);

  // 2. depthwise conv + silu -> u
  conv_silu_k<<<2048, blk, 0, stream>>>(xz, fw_conv_w, bw_conv_w, fw_conv_b, bw_conv_b, u);

  // 3. x_dbl = u @ xproj_w^T   (N=96)
  gemm_bt<<<dim3(8, 1, 2), blk, 0, stream>>>(
      u, xprojw, xprojw + 196608L, (void*)xdbl, 1024, 96, 2048, 2048, 2048, 96,
      (long)1024 * 2048, (long)1024 * 96, nullptr, nullptr, 0, 1, 0, nullptr, 0);

  // 4. delta = softplus(dt @ dt_w^T + dt_b) -> xi cols of xz (ldc=4096)
  gemm_bt<<<dim3(8, 16, 2), blk, 0, stream>>>(
      xdbl, dtw, dtw + 131072L, (void*)delta, 1024, 2048, 64, 96, 64, 4096,
      (long)1024 * 96, (long)1024 * 4096, fw_dt_b, bw_dt_b, 0, 1, 1, nullptr, 0);

  // 5. chunk-parallel scan (2 kernels, coherence via launch boundaries)
  scan_p1<<<dim3(8, NC, 2), blk, 0, stream>>>(xz, u, xdbl, fw_Alog, bw_Alog, hout, sumd);
  scan_p23<<<dim3(8, NC, 2), blk, 0, stream>>>(xz, u, xdbl, fw_Alog, bw_Alog,
                                               fw_Dp, bw_Dp, hout, sumd, g);

  // 6. out-proj + residual + unflip + concat -> fused (bf16 [1024][2048])
  gemm_bt<<<dim3(8, 8, 2), blk, 0, stream>>>(
      g, outw, outw + 2097152L, (void*)fused, 1024, 1024, 2048, 2048, 2048, 1024,
      (long)1024 * 2048, 0L, nullptr, nullptr, 0, 1, 0, x, 1);

  // 7. final proj: fin = fused @ proj_w^T (fp32 out)
  gemm_bt<<<dim3(8, 8, 1), blk, 0, stream>>>(
      fused, projw, projw, (void*)fin, 1024, 1024, 2048, 2048, 2048, 1024,
      0L, 0L, nullptr, nullptr, 0, 0, 0, nullptr, 0);

  // 8. +proj_b, LayerNorm -> d_out (fp32)
  ln_k<<<1024, blk, 0, stream>>>(fin, proj_b, ln_w, ln_b, (float*)d_out);
}

// Round 8
// 365.566 us; speedup vs baseline: 1.3042x; 1.2687x over previous
//
#include <hip/hip_runtime.h>

typedef __bf16 bf16;
typedef __bf16 bf16x8 __attribute__((ext_vector_type(8)));
typedef float  f32x4  __attribute__((ext_vector_type(4)));

#define L_SEQ 1024
#define DM    1024
#define DI    2048
#define DTR   64
#define DSTATE 16
#define XD    96   // DT_RANK + 2*D_STATE
#define NC    32   // scan chunks
#define CS    32   // steps per chunk

__device__ __forceinline__ float bf2f(bf16 v){ return (float)v; }
__device__ __forceinline__ bf16  f2bf(float v){ return (bf16)v; }

// async global->LDS, 16B per lane; LDS dest = wave-uniform base + lane*16
__device__ __forceinline__ void gl_lds16(const bf16* g, bf16* l) {
  __builtin_amdgcn_global_load_lds(
      (const __attribute__((address_space(1))) unsigned int*)g,
      (__attribute__((address_space(3))) unsigned int*)l, 16, 0, 0);
}

// converted-weights element offsets inside wb
#define OFF_X      0L
#define OFF_INW    1048576L            // [2] x 4194304
#define OFF_XPROJ  9437184L            // [2] x 196608
#define OFF_DTW    9830400L            // [2] x 131072
#define OFF_OUTW   10092544L           // [2] x 2097152
#define OFF_PROJW  14286848L           // 2097152
#define CVT_TOTAL  16384000L

// ---------------------------------------------------------------------------
// fp32 -> bf16 conversion of x + all GEMM weights into wb (16.384M elems)
// ---------------------------------------------------------------------------
__global__ __launch_bounds__(256) void cvt_k(
    const float* __restrict__ x,
    const float* __restrict__ inw0, const float* __restrict__ inw1,
    const float* __restrict__ xp0,  const float* __restrict__ xp1,
    const float* __restrict__ dt0,  const float* __restrict__ dt1,
    const float* __restrict__ ow0,  const float* __restrict__ ow1,
    const float* __restrict__ pw,   bf16* __restrict__ wb)
{
  long i = ((long)blockIdx.x * 256 + threadIdx.x) * 8;
  if (i >= CVT_TOTAL) return;
  const float* src; long off;
  if      (i < OFF_INW)                 { src = x;    off = i - OFF_X; }
  else if (i < OFF_INW + 4194304L)      { src = inw0; off = i - OFF_INW; }
  else if (i < OFF_XPROJ)               { src = inw1; off = i - (OFF_INW + 4194304L); }
  else if (i < OFF_XPROJ + 196608L)     { src = xp0;  off = i - OFF_XPROJ; }
  else if (i < OFF_DTW)                 { src = xp1;  off = i - (OFF_XPROJ + 196608L); }
  else if (i < OFF_DTW + 131072L)       { src = dt0;  off = i - OFF_DTW; }
  else if (i < OFF_OUTW)                { src = dt1;  off = i - (OFF_DTW + 131072L); }
  else if (i < OFF_OUTW + 2097152L)     { src = ow0;  off = i - OFF_OUTW; }
  else if (i < OFF_PROJW)               { src = ow1;  off = i - (OFF_OUTW + 2097152L); }
  else                                  { src = pw;   off = i - OFF_PROJW; }
  f32x4 v0 = *(const f32x4*)(src + off);
  f32x4 v1 = *(const f32x4*)(src + off + 4);
  bf16x8 t;
  #pragma unroll
  for (int q = 0; q < 4; q++) { t[q] = (bf16)v0[q]; t[4+q] = (bf16)v1[q]; }
  *(bf16x8*)(wb + i) = t;
}

// ---------------------------------------------------------------------------
// All-bf16 MFMA GEMM, B^T layout: C[m][n] = sum_k A[m][k] * B[n][k]
// Templated tile BMxBN (BK=64), 256 threads = 2x2 waves, wave tile BM/2 x BN/2.
// Staging via global_load_lds (16B/lane) into UNPADDED LDS with XOR-8 chunk
// swizzle (conflict-free, verified R7). Smaller tiles -> more blocks -> higher
// occupancy for the latency-bound small-K GEMMs of this problem.
// fuseRes=1: epilogue writes fused[row][z*DM+gn] = v + xF[row][gn], bf16,
//   with row = (z ? M-1-gm : gm)  (residual + unflip + concat for out-proj)
// ---------------------------------------------------------------------------
template<int BM, int BN>
__global__ __launch_bounds__(256) void gemm_bt(
    const bf16* __restrict__ A, const bf16* __restrict__ B0, const bf16* __restrict__ B1,
    void* __restrict__ Cv,
    int M, int N, int K, int lda, int ldb, int ldc,
    long aOffZ, long cOffZ,
    const float* __restrict__ bias0, const float* __restrict__ bias1,
    int flipA1, int writeBf16, int act,
    const float* __restrict__ xF, int fuseRes)
{
  constexpr int WM = BM / 2, WN = BN / 2;
  constexpr int MI = WM / 16, NJ = WN / 16;
  constexpr int ACALLS = BM / 32;       // gl_lds calls per wave for A tile
  constexpr int BCALLS = BN / 32;

  const int tid  = threadIdx.x;
  const int z    = blockIdx.z;
  const bf16*  Bp   = z ? B1 : B0;
  const float* bias = z ? bias1 : bias0;
  const int flip = z ? flipA1 : 0;
  const int bm = blockIdx.x * BM;
  const int bn = blockIdx.y * BN;

  __shared__ bf16 As[BM * 64];   // unpadded (global_load_lds requirement)
  __shared__ bf16 Bs[BN * 64];

  f32x4 acc[MI][NJ];
  #pragma unroll
  for (int i=0;i<MI;i++)
    #pragma unroll
    for (int j=0;j<NJ;j++) { acc[i][j][0]=0.f; acc[i][j][1]=0.f; acc[i][j][2]=0.f; acc[i][j][3]=0.f; }

  const int wave = tid >> 6;
  const int lane = tid & 63;
  const int wm = (wave >> 1) * WM;
  const int wn = (wave & 1) * WN;
  const int fr  = lane & 15;         // fragment row
  const int frx = fr & 7;            // xor key (row&7 == fr&7: offsets are %8==0)
  const int kqc = lane >> 4;         // quad chunk (0..3)

  // staging sources: LDS chunk s = (wave*CALLS+t)*64 + lane; r=s>>3; j=(s&7)^(r&7)
  const bf16* aSrc[ACALLS];
  int aOff[ACALLS];
  #pragma unroll
  for (int t = 0; t < ACALLS; t++) {
    int s = (wave * ACALLS + t) * 64 + lane;
    int r = s >> 3;
    int j = (s & 7) ^ (r & 7);
    int ar = bm + r;
    int agr = flip ? (M - 1 - ar) : ar;
    aSrc[t] = A + (long)z * aOffZ + (long)agr * lda + j * 8;
    aOff[t] = (wave * ACALLS + t) * 512;
  }
  const bf16* bSrc[BCALLS];
  int bOff[BCALLS];
  #pragma unroll
  for (int t = 0; t < BCALLS; t++) {
    int s = (wave * BCALLS + t) * 64 + lane;
    int r = s >> 3;
    int j = (s & 7) ^ (r & 7);
    int br = bn + r; if (br > N - 1) br = N - 1;   // clamp (cols skipped later)
    bSrc[t] = Bp + (long)br * ldb + j * 8;
    bOff[t] = (wave * BCALLS + t) * 512;
  }

  for (int k0 = 0; k0 < K; k0 += 64) {
    #pragma unroll
    for (int t = 0; t < ACALLS; t++) gl_lds16(aSrc[t] + k0, &As[aOff[t]]);
    #pragma unroll
    for (int t = 0; t < BCALLS; t++) gl_lds16(bSrc[t] + k0, &Bs[bOff[t]]);
    __syncthreads();

    #pragma unroll
    for (int ks8 = 0; ks8 < 8; ks8 += 4) {   // chunk-base 0, 4 (= k 0, 32)
      bf16x8 af[MI], bfr[NJ];
      #pragma unroll
      for (int i=0;i<MI;i++) {
        int row = wm + i*16 + fr;
        af[i]  = *(const bf16x8*)&As[(row * 8 + ((ks8 + kqc) ^ frx)) * 8];
      }
      #pragma unroll
      for (int j=0;j<NJ;j++) {
        int row = wn + j*16 + fr;
        bfr[j] = *(const bf16x8*)&Bs[(row * 8 + ((ks8 + kqc) ^ frx)) * 8];
      }
      #pragma unroll
      for (int i=0;i<MI;i++)
        #pragma unroll
        for (int j=0;j<NJ;j++)
          acc[i][j] = __builtin_amdgcn_mfma_f32_16x16x32_bf16(af[i], bfr[j], acc[i][j], 0, 0, 0);
    }
    __syncthreads();
  }

  const int rr = (lane >> 4) * 4;
  const int cc = lane & 15;
  #pragma unroll
  for (int i=0;i<MI;i++) {
    #pragma unroll
    for (int j=0;j<NJ;j++) {
      int gn = bn + wn + j*16 + cc;
      if (gn >= N) continue;
      float bv = bias ? bias[gn] : 0.f;
      #pragma unroll
      for (int r=0;r<4;r++) {
        int gm = bm + wm + i*16 + rr + r;
        float v = acc[i][j][r] + bv;
        if (fuseRes) {
          long row = z ? (long)(M - 1 - gm) : (long)gm;
          float o = v + xF[row * DM + gn];
          ((bf16*)Cv)[row * (2 * DM) + (long)z * DM + gn] = f2bf(o);
        } else {
          if (act == 1) v = (v > 20.f) ? v : log1pf(__expf(v));  // softplus
          long idx = (long)z * cOffZ + (long)gm * ldc + gn;
          if (writeBf16) ((bf16*)Cv)[idx] = f2bf(v);
          else           ((float*)Cv)[idx] = v;
        }
      }
    }
  }
}

// ---------------------------------------------------------------------------
// depthwise causal conv(4) + bias + silu : u[dir][l][d], 8 channels/thread
// ---------------------------------------------------------------------------
__global__ __launch_bounds__(256) void conv_silu_k(
    const bf16* __restrict__ xz, const float* __restrict__ cw0, const float* __restrict__ cw1,
    const float* __restrict__ cb0, const float* __restrict__ cb1, bf16* __restrict__ u)
{
  int gid = blockIdx.x * 256 + threadIdx.x;     // over 2*L*DI/8 = 524288
  int dir = gid >> 18;
  int rem = gid & ((1 << 18) - 1);
  int l = rem >> 8;
  int d0 = (rem & 255) * 8;
  const float* w = dir ? cw1 : cw0;
  const float* b = dir ? cb1 : cb0;
  const bf16* xzd = xz + (long)dir * L_SEQ * (2 * DI);
  float acc[8];
  #pragma unroll
  for (int q = 0; q < 8; q++) acc[q] = b[d0 + q];
  #pragma unroll
  for (int j = 0; j < 4; j++) {
    int ll = l - 3 + j;
    if (ll < 0) continue;
    bf16x8 xv = *(const bf16x8*)(xzd + (long)ll * (2 * DI) + d0);
    #pragma unroll
    for (int q = 0; q < 8; q++) acc[q] += w[(d0 + q) * 4 + j] * bf2f(xv[q]);
  }
  bf16x8 o;
  #pragma unroll
  for (int q = 0; q < 8; q++) {
    float s = acc[q] / (1.f + __expf(-acc[q]));
    o[q] = f2bf(s);
  }
  *(bf16x8*)(u + (long)dir * L_SEQ * DI + (long)l * DI + d0) = o;
}

// ---------------------------------------------------------------------------
// Chunk-parallel selective scan, 2 kernels, no grid sync (XCD-coherence safe)
// ---------------------------------------------------------------------------
__global__ __launch_bounds__(256) void scan_p1(
    const bf16* __restrict__ xz, const bf16* __restrict__ u, const bf16* __restrict__ xdbl,
    const float* __restrict__ Alog0, const float* __restrict__ Alog1,
    bf16* __restrict__ hout, float* __restrict__ sumd)
{
  const int tid = threadIdx.x;
  const int c   = blockIdx.y;
  const int dir = blockIdx.z;
  const int d   = blockIdx.x * 256 + tid;
  const float* Alog = dir ? Alog1 : Alog0;
  const bf16* dl = xz + (long)dir * L_SEQ * (2 * DI);       // delta in xi cols
  const bf16* ud = u  + (long)dir * L_SEQ * DI;
  const bf16* xd = xdbl + (long)dir * L_SEQ * XD;
  const int l0 = c * CS;

  __shared__ float lb[CS][16];
  {
    int i = tid * 2;
    int ll = i >> 4, n = i & 15;
    const bf16* p = xd + (long)(l0 + ll) * XD + DTR + n;
    lb[ll][n]     = bf2f(p[0]);
    lb[ll][n + 1] = bf2f(p[1]);
  }
  __syncthreads();

  float An[16], h[16];
  #pragma unroll
  for (int n = 0; n < 16; n++) { An[n] = -__expf(Alog[d * 16 + n]); h[n] = 0.f; }
  float sd = 0.f;

  #pragma unroll 4
  for (int ll = 0; ll < CS; ll++) {
    int l = l0 + ll;
    float dlt = bf2f(dl[(long)l * (2 * DI) + d]);
    float uu  = bf2f(ud[(long)l * DI + d]);
    sd += dlt;
    float du = dlt * uu;
    #pragma unroll
    for (int n = 0; n < 16; n++) {
      float a = __expf(dlt * An[n]);
      h[n] = h[n] * a + du * lb[ll][n];
    }
  }

  bf16* hp = hout + (((long)dir * NC + c) * DI + d) * 16;
  bf16x8 o0, o1;
  #pragma unroll
  for (int n = 0; n < 8; n++) { o0[n] = f2bf(h[n]); o1[n] = f2bf(h[8 + n]); }
  *(bf16x8*)hp = o0;
  *(bf16x8*)(hp + 8) = o1;
  sumd[((long)dir * NC + c) * DI + d] = sd;
}

__global__ __launch_bounds__(256) void scan_p23(
    const bf16* xz, const bf16* u, const bf16* __restrict__ xdbl,
    const float* __restrict__ Alog0, const float* __restrict__ Alog1,
    const float* __restrict__ Dp0, const float* __restrict__ Dp1,
    const bf16* __restrict__ hout, const float* __restrict__ sumd, bf16* g)
{
  const int tid = threadIdx.x;
  const int c   = blockIdx.y;
  const int dir = blockIdx.z;
  const int d   = blockIdx.x * 256 + tid;
  const float* Alog = dir ? Alog1 : Alog0;
  const float* Dp   = dir ? Dp1 : Dp0;
  const bf16* row0 = xz + (long)dir * L_SEQ * (2 * DI);   // delta @ +d, z @ +DI+d
  const bf16* ud   = u  + (long)dir * L_SEQ * DI;
  const bf16* xd   = xdbl + (long)dir * L_SEQ * XD;
  bf16* gd = g + (long)dir * L_SEQ * DI;
  const int l0 = c * CS;

  __shared__ float lb[CS][16];
  __shared__ float lc[CS][16];
  {
    int i = tid * 4;
    int ll = i >> 5, j = i & 31;
    const bf16* p = xd + (long)(l0 + ll) * XD + DTR + j;
    #pragma unroll
    for (int q = 0; q < 4; q++) {
      int jj = j + q;
      float v = bf2f(p[q]);
      if (jj < 16) lb[ll][jj] = v; else lc[ll][jj - 16] = v;
    }
  }
  __syncthreads();

  float An[16], h[16];
  #pragma unroll
  for (int n = 0; n < 16; n++) {
    An[n] = -__expf(Alog[d * 16 + n]);
    h[n] = 0.f;
  }

  // prefix combine: h_start for chunk c (redundant per-chunk recompute)
  for (int cp = 0; cp < c; cp++) {
    long base = ((long)dir * NC + cp) * DI + d;
    float sd = sumd[base];
    const bf16* hp = hout + base * 16;
    bf16x8 s0 = *(const bf16x8*)hp;
    bf16x8 s1 = *(const bf16x8*)(hp + 8);
    #pragma unroll
    for (int n = 0; n < 16; n++) {
      float P = __expf(An[n] * sd);
      float S = bf2f(n < 8 ? s0[n & 7] : s1[n & 7]);
      h[n] = P * h[n] + S;
    }
  }

  const float Dpv = Dp[d];
  #pragma unroll 4
  for (int ll = 0; ll < CS; ll++) {
    int l = l0 + ll;
    float dlt = bf2f(row0[(long)l * (2 * DI) + d]);
    float zv  = bf2f(row0[(long)l * (2 * DI) + DI + d]);
    float uu  = bf2f(ud[(long)l * DI + d]);
    float du = dlt * uu;
    float y = 0.f;
    #pragma unroll
    for (int n = 0; n < 16; n++) {
      float a = __expf(dlt * An[n]);
      h[n] = h[n] * a + du * lb[ll][n];
      y += h[n] * lc[ll][n];
    }
    y += uu * Dpv;
    float sz = zv / (1.f + __expf(-zv));
    gd[(long)l * DI + d] = f2bf(y * sz);
  }
}

// ---------------------------------------------------------------------------
// +proj_b then LayerNorm over last dim (1024), write fp32 out
// ---------------------------------------------------------------------------
__global__ __launch_bounds__(256) void ln_k(
    const float* __restrict__ fin, const float* __restrict__ pb,
    const float* __restrict__ lnw, const float* __restrict__ lnb, float* __restrict__ out)
{
  int row = blockIdx.x;
  int tid = threadIdx.x;
  float v[4]; float s1 = 0.f, s2 = 0.f;
  #pragma unroll
  for (int j = 0; j < 4; j++) {
    int c = tid + j * 256;
    v[j] = fin[(long)row * DM + c] + pb[c];
    s1 += v[j]; s2 += v[j] * v[j];
  }
  #pragma unroll
  for (int off = 32; off; off >>= 1) { s1 += __shfl_down(s1, off); s2 += __shfl_down(s2, off); }
  __shared__ float red[8];
  int wave = tid >> 6, lane = tid & 63;
  if (lane == 0) { red[wave] = s1; red[4 + wave] = s2; }
  __syncthreads();
  float t1 = red[0] + red[1] + red[2] + red[3];
  float t2 = red[4] + red[5] + red[6] + red[7];
  float mu = t1 / DM;
  float var = t2 / DM - mu * mu;
  float inv = rsqrtf(var + 1e-5f);
  #pragma unroll
  for (int j = 0; j < 4; j++) {
    int c = tid + j * 256;
    out[(long)row * DM + c] = (v[j] - mu) * inv * lnw[c] + lnb[c];
  }
}

// ---------------------------------------------------------------------------
extern "C" void kernel_launch(void* const* d_in, const int* in_sizes, int n_in,
                              void* d_out, int out_size, void* d_ws, size_t ws_size,
                              hipStream_t stream)
{
  const float* x         = (const float*)d_in[0];
  const float* fw_conv_w = (const float*)d_in[2];
  const float* fw_conv_b = (const float*)d_in[3];
  const float* fw_dt_b   = (const float*)d_in[6];
  const float* fw_Alog   = (const float*)d_in[7];
  const float* fw_Dp     = (const float*)d_in[8];
  const float* bw_conv_w = (const float*)d_in[11];
  const float* bw_conv_b = (const float*)d_in[12];
  const float* bw_dt_b   = (const float*)d_in[15];
  const float* bw_Alog   = (const float*)d_in[16];
  const float* bw_Dp     = (const float*)d_in[17];
  const float* proj_b    = (const float*)d_in[20];
  const float* ln_w      = (const float*)d_in[21];
  const float* ln_b      = (const float*)d_in[22];

  // workspace layout (peak ~62.3 MB):
  //   xz bf16 [2][1024][4096]  @ 0..16MB  (delta overwrites xi cols; dead after scan)
  //   u/g bf16 [2][1024][2048] @ 16..24MB (g in-place over u)
  //   xdbl bf16 [2][1024][96]  @ 24..24.4MB
  //   sumd f32 [2][32][2048]   @ 25..25.5MB
  //   hout bf16 [2][32][2048][16] @ 26..30MB
  //   wb bf16 (converted x + weights) @ 30..61.3MB
  //   phase 2 (over dead xz): fused bf16 [1024][2048] @0..4MB, fin f32 @4..8MB
  char* ws = (char*)d_ws;
  const size_t MB = 1024 * 1024;
  bf16*  xz    = (bf16*)(ws + 0);
  bf16*  u     = (bf16*)(ws + 16 * MB);
  bf16*  xdbl  = (bf16*)(ws + 24 * MB);
  float* sumd  = (float*)(ws + 25 * MB);
  bf16*  hout  = (bf16*)(ws + 26 * MB);
  bf16*  wb    = (bf16*)(ws + 30 * MB);
  bf16*  g     = u;
  bf16*  delta = xz;                      // xi columns, stride 4096
  bf16*  fused = (bf16*)(ws + 0);
  float* fin   = (float*)(ws + 4 * MB);

  bf16* xb     = wb + OFF_X;
  bf16* inw    = wb + OFF_INW;     // [2][4096][1024]
  bf16* xprojw = wb + OFF_XPROJ;   // [2][96][2048]
  bf16* dtw    = wb + OFF_DTW;     // [2][2048][64]
  bf16* outw   = wb + OFF_OUTW;    // [2][1024][2048]
  bf16* projw  = wb + OFF_PROJW;   // [1024][2048]

  dim3 blk(256);

  // 0. convert x + weights to bf16
  cvt_k<<<(CVT_TOTAL / 8 + 255) / 256, blk, 0, stream>>>(
      x, (const float*)d_in[1], (const float*)d_in[10],
      (const float*)d_in[4], (const float*)d_in[13],
      (const float*)d_in[5], (const float*)d_in[14],
      (const float*)d_in[9], (const float*)d_in[18],
      (const float*)d_in[19], wb);

  // 1. in-proj: xz[dir] = (flip?)xb @ in_w^T  (M=1024,N=4096,K=1024) 1024 blocks
  gemm_bt<64,128><<<dim3(16, 32, 2), blk, 0, stream>>>(
      xb, inw, inw + 4194304L, (void*)xz, 1024, 4096, 1024, 1024, 1024, 4096,
      0L, (long)1024 * 4096, nullptr, nullptr, 1, 1, 0, nullptr, 0);

  // 2. depthwise conv + silu -> u
  conv_silu_k<<<2048, blk, 0, stream>>>(xz, fw_conv_w, bw_conv_w, fw_conv_b, bw_conv_b, u);

  // 3. x_dbl = u @ xproj_w^T   (N=96)  128 blocks
  gemm_bt<32,64><<<dim3(32, 2, 2), blk, 0, stream>>>(
      u, xprojw, xprojw + 196608L, (void*)xdbl, 1024, 96, 2048, 2048, 2048, 96,
      (long)1024 * 2048, (long)1024 * 96, nullptr, nullptr, 0, 1, 0, nullptr, 0);

  // 4. delta = softplus(dt @ dt_w^T + dt_b) -> xi cols of xz (ldc=4096)  512 blocks
  gemm_bt<64,128><<<dim3(16, 16, 2), blk, 0, stream>>>(
      xdbl, dtw, dtw + 131072L, (void*)delta, 1024, 2048, 64, 96, 64, 4096,
      (long)1024 * 96, (long)1024 * 4096, fw_dt_b, bw_dt_b, 0, 1, 1, nullptr, 0);

  // 5. chunk-parallel scan (2 kernels, coherence via launch boundaries)
  scan_p1<<<dim3(8, NC, 2), blk, 0, stream>>>(xz, u, xdbl, fw_Alog, bw_Alog, hout, sumd);
  scan_p23<<<dim3(8, NC, 2), blk, 0, stream>>>(xz, u, xdbl, fw_Alog, bw_Alog,
                                               fw_Dp, bw_Dp, hout, sumd, g);

  // 6. out-proj + residual + unflip + concat -> fused (bf16 [1024][2048]) 1024 blocks
  gemm_bt<32,64><<<dim3(32, 16, 2), blk, 0, stream>>>(
      g, outw, outw + 2097152L, (void*)fused, 1024, 1024, 2048, 2048, 2048, 1024,
      (long)1024 * 2048, 0L, nullptr, nullptr, 0, 1, 0, x, 1);

  // 7. final proj: fin = fused @ proj_w^T (fp32 out)  512 blocks
  gemm_bt<32,64><<<dim3(32, 16, 1), blk, 0, stream>>>(
      fused, projw, projw, (void*)fin, 1024, 1024, 2048, 2048, 2048, 1024,
      0L, 0L, nullptr, nullptr, 0, 0, 0, nullptr, 0);

  // 8. +proj_b, LayerNorm -> d_out (fp32)
  ln_k<<<1024, blk, 0, stream>>>(fin, proj_b, ln_w, ln_b, (float*)d_out);
}

// Round 9
// 336.448 us; speedup vs baseline: 1.4171x; 1.0865x over previous
//
#include <hip/hip_runtime.h>

typedef __bf16 bf16;
typedef __bf16 bf16x8 __attribute__((ext_vector_type(8)));
typedef float  f32x4  __attribute__((ext_vector_type(4)));

#define L_SEQ 1024
#define DM    1024
#define DI    2048
#define DTR   64
#define DSTATE 16
#define XD    96   // DT_RANK + 2*D_STATE
#define NC    64   // scan chunks
#define CS    16   // steps per chunk

__device__ __forceinline__ float bf2f(bf16 v){ return (float)v; }
__device__ __forceinline__ bf16  f2bf(float v){ return (bf16)v; }

// async global->LDS, 16B per lane; LDS dest = wave-uniform base + lane*16
__device__ __forceinline__ void gl_lds16(const bf16* g, bf16* l) {
  __builtin_amdgcn_global_load_lds(
      (const __attribute__((address_space(1))) unsigned int*)g,
      (__attribute__((address_space(3))) unsigned int*)l, 16, 0, 0);
}

// converted-weights element offsets inside wb
#define OFF_X      0L
#define OFF_INW    1048576L            // [2] x 4194304
#define OFF_XPROJ  9437184L            // [2] x 196608
#define OFF_DTW    9830400L            // [2] x 131072
#define OFF_OUTW   10092544L           // [2] x 2097152
#define OFF_PROJW  14286848L           // 2097152
#define CVT_TOTAL  16384000L

// ---------------------------------------------------------------------------
// fp32 -> bf16 conversion of x + all GEMM weights into wb (16.384M elems)
// ---------------------------------------------------------------------------
__global__ __launch_bounds__(256) void cvt_k(
    const float* __restrict__ x,
    const float* __restrict__ inw0, const float* __restrict__ inw1,
    const float* __restrict__ xp0,  const float* __restrict__ xp1,
    const float* __restrict__ dt0,  const float* __restrict__ dt1,
    const float* __restrict__ ow0,  const float* __restrict__ ow1,
    const float* __restrict__ pw,   bf16* __restrict__ wb)
{
  long i = ((long)blockIdx.x * 256 + threadIdx.x) * 8;
  if (i >= CVT_TOTAL) return;
  const float* src; long off;
  if      (i < OFF_INW)                 { src = x;    off = i - OFF_X; }
  else if (i < OFF_INW + 4194304L)      { src = inw0; off = i - OFF_INW; }
  else if (i < OFF_XPROJ)               { src = inw1; off = i - (OFF_INW + 4194304L); }
  else if (i < OFF_XPROJ + 196608L)     { src = xp0;  off = i - OFF_XPROJ; }
  else if (i < OFF_DTW)                 { src = xp1;  off = i - (OFF_XPROJ + 196608L); }
  else if (i < OFF_DTW + 131072L)       { src = dt0;  off = i - OFF_DTW; }
  else if (i < OFF_OUTW)                { src = dt1;  off = i - (OFF_DTW + 131072L); }
  else if (i < OFF_OUTW + 2097152L)     { src = ow0;  off = i - OFF_OUTW; }
  else if (i < OFF_PROJW)               { src = ow1;  off = i - (OFF_OUTW + 2097152L); }
  else                                  { src = pw;   off = i - OFF_PROJW; }
  f32x4 v0 = *(const f32x4*)(src + off);
  f32x4 v1 = *(const f32x4*)(src + off + 4);
  bf16x8 t;
  #pragma unroll
  for (int q = 0; q < 4; q++) { t[q] = (bf16)v0[q]; t[4+q] = (bf16)v1[q]; }
  *(bf16x8*)(wb + i) = t;
}

// ---------------------------------------------------------------------------
// All-bf16 MFMA GEMM, B^T layout: C[m][n] = sum_k A[m][k] * B[n][k]
// Templated tile BMxBN (BK=64), 256 threads = 2x2 waves. global_load_lds
// staging, XOR-8 swizzle (conflict-free, verified R7/R8).
// ---------------------------------------------------------------------------
template<int BM, int BN>
__global__ __launch_bounds__(256) void gemm_bt(
    const bf16* __restrict__ A, const bf16* __restrict__ B0, const bf16* __restrict__ B1,
    void* __restrict__ Cv,
    int M, int N, int K, int lda, int ldb, int ldc,
    long aOffZ, long cOffZ,
    const float* __restrict__ bias0, const float* __restrict__ bias1,
    int flipA1, int writeBf16, int act,
    const float* __restrict__ xF, int fuseRes)
{
  constexpr int WM = BM / 2, WN = BN / 2;
  constexpr int MI = WM / 16, NJ = WN / 16;
  constexpr int ACALLS = BM / 32;
  constexpr int BCALLS = BN / 32;

  const int tid  = threadIdx.x;
  const int z    = blockIdx.z;
  const bf16*  Bp   = z ? B1 : B0;
  const float* bias = z ? bias1 : bias0;
  const int flip = z ? flipA1 : 0;
  const int bm = blockIdx.x * BM;
  const int bn = blockIdx.y * BN;

  __shared__ bf16 As[BM * 64];
  __shared__ bf16 Bs[BN * 64];

  f32x4 acc[MI][NJ];
  #pragma unroll
  for (int i=0;i<MI;i++)
    #pragma unroll
    for (int j=0;j<NJ;j++) { acc[i][j][0]=0.f; acc[i][j][1]=0.f; acc[i][j][2]=0.f; acc[i][j][3]=0.f; }

  const int wave = tid >> 6;
  const int lane = tid & 63;
  const int wm = (wave >> 1) * WM;
  const int wn = (wave & 1) * WN;
  const int fr  = lane & 15;
  const int frx = fr & 7;
  const int kqc = lane >> 4;

  const bf16* aSrc[ACALLS];
  int aOff[ACALLS];
  #pragma unroll
  for (int t = 0; t < ACALLS; t++) {
    int s = (wave * ACALLS + t) * 64 + lane;
    int r = s >> 3;
    int j = (s & 7) ^ (r & 7);
    int ar = bm + r;
    int agr = flip ? (M - 1 - ar) : ar;
    aSrc[t] = A + (long)z * aOffZ + (long)agr * lda + j * 8;
    aOff[t] = (wave * ACALLS + t) * 512;
  }
  const bf16* bSrc[BCALLS];
  int bOff[BCALLS];
  #pragma unroll
  for (int t = 0; t < BCALLS; t++) {
    int s = (wave * BCALLS + t) * 64 + lane;
    int r = s >> 3;
    int j = (s & 7) ^ (r & 7);
    int br = bn + r; if (br > N - 1) br = N - 1;
    bSrc[t] = Bp + (long)br * ldb + j * 8;
    bOff[t] = (wave * BCALLS + t) * 512;
  }

  for (int k0 = 0; k0 < K; k0 += 64) {
    #pragma unroll
    for (int t = 0; t < ACALLS; t++) gl_lds16(aSrc[t] + k0, &As[aOff[t]]);
    #pragma unroll
    for (int t = 0; t < BCALLS; t++) gl_lds16(bSrc[t] + k0, &Bs[bOff[t]]);
    __syncthreads();

    #pragma unroll
    for (int ks8 = 0; ks8 < 8; ks8 += 4) {
      bf16x8 af[MI], bfr[NJ];
      #pragma unroll
      for (int i=0;i<MI;i++) {
        int row = wm + i*16 + fr;
        af[i]  = *(const bf16x8*)&As[(row * 8 + ((ks8 + kqc) ^ frx)) * 8];
      }
      #pragma unroll
      for (int j=0;j<NJ;j++) {
        int row = wn + j*16 + fr;
        bfr[j] = *(const bf16x8*)&Bs[(row * 8 + ((ks8 + kqc) ^ frx)) * 8];
      }
      #pragma unroll
      for (int i=0;i<MI;i++)
        #pragma unroll
        for (int j=0;j<NJ;j++)
          acc[i][j] = __builtin_amdgcn_mfma_f32_16x16x32_bf16(af[i], bfr[j], acc[i][j], 0, 0, 0);
    }
    __syncthreads();
  }

  const int rr = (lane >> 4) * 4;
  const int cc = lane & 15;
  #pragma unroll
  for (int i=0;i<MI;i++) {
    #pragma unroll
    for (int j=0;j<NJ;j++) {
      int gn = bn + wn + j*16 + cc;
      if (gn >= N) continue;
      float bv = bias ? bias[gn] : 0.f;
      #pragma unroll
      for (int r=0;r<4;r++) {
        int gm = bm + wm + i*16 + rr + r;
        float v = acc[i][j][r] + bv;
        if (fuseRes) {
          long row = z ? (long)(M - 1 - gm) : (long)gm;
          float o = v + xF[row * DM + gn];
          ((bf16*)Cv)[row * (2 * DM) + (long)z * DM + gn] = f2bf(o);
        } else {
          if (act == 1) v = (v > 20.f) ? v : log1pf(__expf(v));  // softplus
          long idx = (long)z * cOffZ + (long)gm * ldc + gn;
          if (writeBf16) ((bf16*)Cv)[idx] = f2bf(v);
          else           ((float*)Cv)[idx] = v;
        }
      }
    }
  }
}

// ---------------------------------------------------------------------------
// depthwise causal conv(4) + bias + silu : u[dir][l][d], 8 channels/thread
// ---------------------------------------------------------------------------
__global__ __launch_bounds__(256) void conv_silu_k(
    const bf16* __restrict__ xz, const float* __restrict__ cw0, const float* __restrict__ cw1,
    const float* __restrict__ cb0, const float* __restrict__ cb1, bf16* __restrict__ u)
{
  int gid = blockIdx.x * 256 + threadIdx.x;     // over 2*L*DI/8 = 524288
  int dir = gid >> 18;
  int rem = gid & ((1 << 18) - 1);
  int l = rem >> 8;
  int d0 = (rem & 255) * 8;
  const float* w = dir ? cw1 : cw0;
  const float* b = dir ? cb1 : cb0;
  const bf16* xzd = xz + (long)dir * L_SEQ * (2 * DI);
  float acc[8];
  #pragma unroll
  for (int q = 0; q < 8; q++) acc[q] = b[d0 + q];
  #pragma unroll
  for (int j = 0; j < 4; j++) {
    int ll = l - 3 + j;
    if (ll < 0) continue;
    bf16x8 xv = *(const bf16x8*)(xzd + (long)ll * (2 * DI) + d0);
    #pragma unroll
    for (int q = 0; q < 8; q++) acc[q] += w[(d0 + q) * 4 + j] * bf2f(xv[q]);
  }
  bf16x8 o;
  #pragma unroll
  for (int q = 0; q < 8; q++) {
    float s = acc[q] / (1.f + __expf(-acc[q]));
    o[q] = f2bf(s);
  }
  *(bf16x8*)(u + (long)dir * L_SEQ * DI + (long)l * DI + d0) = o;
}

// ---------------------------------------------------------------------------
// Chunk-parallel selective scan, 3 kernels (XCD-coherence via launch bounds).
// NC=64 chunks of CS=16. p1/p3 PRELOAD the whole chunk's inputs into registers
// before the recurrence -> the 16-step h-chain runs with zero memory stalls.
// ---------------------------------------------------------------------------
__global__ __launch_bounds__(256) void scan_p1(
    const bf16* __restrict__ xz, const bf16* __restrict__ u, const bf16* __restrict__ xdbl,
    const float* __restrict__ Alog0, const float* __restrict__ Alog1,
    bf16* __restrict__ hout, float* __restrict__ sumd)
{
  const int tid = threadIdx.x;
  const int c   = blockIdx.y;
  const int dir = blockIdx.z;
  const int d   = blockIdx.x * 256 + tid;
  const float* Alog = dir ? Alog1 : Alog0;
  const bf16* dl = xz + (long)dir * L_SEQ * (2 * DI);       // delta in xi cols
  const bf16* ud = u  + (long)dir * L_SEQ * DI;
  const bf16* xd = xdbl + (long)dir * L_SEQ * XD;
  const int l0 = c * CS;

  __shared__ float lb[CS][16];
  {
    int ll = tid >> 4, n = tid & 15;    // CS*16 = 256 = one elem/thread
    lb[ll][n] = bf2f(xd[(long)(l0 + ll) * XD + DTR + n]);
  }

  // preload whole chunk's delta/u (addresses data-independent)
  float dl_r[CS], uu_r[CS];
  #pragma unroll
  for (int s = 0; s < CS; s++) {
    dl_r[s] = bf2f(dl[(long)(l0 + s) * (2 * DI) + d]);
    uu_r[s] = bf2f(ud[(long)(l0 + s) * DI + d]);
  }
  __syncthreads();

  float An[16], h[16];
  #pragma unroll
  for (int n = 0; n < 16; n++) { An[n] = -__expf(Alog[d * 16 + n]); h[n] = 0.f; }
  float sd = 0.f;

  #pragma unroll
  for (int ll = 0; ll < CS; ll++) {
    float dlt = dl_r[ll];
    sd += dlt;
    float du = dlt * uu_r[ll];
    #pragma unroll
    for (int n = 0; n < 16; n++) {
      float a = __expf(dlt * An[n]);
      h[n] = h[n] * a + du * lb[ll][n];
    }
  }

  bf16* hp = hout + (((long)dir * NC + c) * DI + d) * 16;
  bf16x8 o0, o1;
  #pragma unroll
  for (int n = 0; n < 8; n++) { o0[n] = f2bf(h[n]); o1[n] = f2bf(h[8 + n]); }
  *(bf16x8*)hp = o0;
  *(bf16x8*)(hp + 8) = o1;
  sumd[((long)dir * NC + c) * DI + d] = sd;
}

__global__ __launch_bounds__(256) void scan_p2(
    const float* __restrict__ Alog0, const float* __restrict__ Alog1,
    bf16* hout, const float* __restrict__ sumd)
{
  int g = blockIdx.x * 256 + threadIdx.x;   // 2*2048*16 = 65536
  int dir = g >> 15;
  int rem = g & 32767;
  int d = rem >> 4;
  int n = rem & 15;
  const float* Alog = dir ? Alog1 : Alog0;
  float An = -__expf(Alog[d * 16 + n]);
  float hs = 0.f;
  #pragma unroll 4
  for (int c = 0; c < NC; c++) {
    long base = ((long)dir * NC + c) * DI + d;
    float tmp = bf2f(hout[base * 16 + n]);
    float P = __expf(An * sumd[base]);
    hout[base * 16 + n] = f2bf(hs);   // h_start for chunk c
    hs = P * hs + tmp;
  }
}

__global__ __launch_bounds__(256) void scan_p3(
    const bf16* xz, const bf16* u, const bf16* __restrict__ xdbl,
    const float* __restrict__ Alog0, const float* __restrict__ Alog1,
    const float* __restrict__ Dp0, const float* __restrict__ Dp1,
    const bf16* __restrict__ hout, bf16* g)
{
  const int tid = threadIdx.x;
  const int c   = blockIdx.y;
  const int dir = blockIdx.z;
  const int d   = blockIdx.x * 256 + tid;
  const float* Alog = dir ? Alog1 : Alog0;
  const float* Dp   = dir ? Dp1 : Dp0;
  const bf16* row0 = xz + (long)dir * L_SEQ * (2 * DI);   // delta @ +d, z @ +DI+d
  const bf16* ud   = u  + (long)dir * L_SEQ * DI;
  const bf16* xd   = xdbl + (long)dir * L_SEQ * XD;
  bf16* gd = g + (long)dir * L_SEQ * DI;
  const int l0 = c * CS;

  __shared__ float lb[CS][16];
  __shared__ float lc[CS][16];
  {
    int i = tid * 2;                   // CS*32 = 512, 2 consecutive/thread
    int ll = i >> 5, j = i & 31;       // j even
    const bf16* p = xd + (long)(l0 + ll) * XD + DTR + j;
    float v0 = bf2f(p[0]), v1 = bf2f(p[1]);
    if (j < 16) { lb[ll][j] = v0; lb[ll][j + 1] = v1; }
    else        { lc[ll][j - 16] = v0; lc[ll][j - 15] = v1; }
  }

  // preload whole chunk's delta/z/u + h_start (addresses data-independent)
  float dl_r[CS], uu_r[CS], zv_r[CS];
  #pragma unroll
  for (int s = 0; s < CS; s++) {
    dl_r[s] = bf2f(row0[(long)(l0 + s) * (2 * DI) + d]);
    zv_r[s] = bf2f(row0[(long)(l0 + s) * (2 * DI) + DI + d]);
    uu_r[s] = bf2f(ud[(long)(l0 + s) * DI + d]);
  }
  const bf16* hp = hout + (((long)dir * NC + c) * DI + d) * 16;
  bf16x8 h0 = *(const bf16x8*)hp;
  bf16x8 h1 = *(const bf16x8*)(hp + 8);
  __syncthreads();

  float An[16], h[16];
  #pragma unroll
  for (int n = 0; n < 16; n++) {
    An[n] = -__expf(Alog[d * 16 + n]);
    h[n] = bf2f(n < 8 ? h0[n & 7] : h1[n & 7]);
  }
  const float Dpv = Dp[d];

  #pragma unroll
  for (int ll = 0; ll < CS; ll++) {
    float dlt = dl_r[ll];
    float du = dlt * uu_r[ll];
    float y = 0.f;
    #pragma unroll
    for (int n = 0; n < 16; n++) {
      float a = __expf(dlt * An[n]);
      h[n] = h[n] * a + du * lb[ll][n];
      y += h[n] * lc[ll][n];
    }
    y += uu_r[ll] * Dpv;
    float zv = zv_r[ll];
    float sz = zv / (1.f + __expf(-zv));
    gd[(long)(l0 + ll) * DI + d] = f2bf(y * sz);
  }
}

// ---------------------------------------------------------------------------
// +proj_b then LayerNorm over last dim (1024), write fp32 out
// ---------------------------------------------------------------------------
__global__ __launch_bounds__(256) void ln_k(
    const float* __restrict__ fin, const float* __restrict__ pb,
    const float* __restrict__ lnw, const float* __restrict__ lnb, float* __restrict__ out)
{
  int row = blockIdx.x;
  int tid = threadIdx.x;
  float v[4]; float s1 = 0.f, s2 = 0.f;
  #pragma unroll
  for (int j = 0; j < 4; j++) {
    int c = tid + j * 256;
    v[j] = fin[(long)row * DM + c] + pb[c];
    s1 += v[j]; s2 += v[j] * v[j];
  }
  #pragma unroll
  for (int off = 32; off; off >>= 1) { s1 += __shfl_down(s1, off); s2 += __shfl_down(s2, off); }
  __shared__ float red[8];
  int wave = tid >> 6, lane = tid & 63;
  if (lane == 0) { red[wave] = s1; red[4 + wave] = s2; }
  __syncthreads();
  float t1 = red[0] + red[1] + red[2] + red[3];
  float t2 = red[4] + red[5] + red[6] + red[7];
  float mu = t1 / DM;
  float var = t2 / DM - mu * mu;
  float inv = rsqrtf(var + 1e-5f);
  #pragma unroll
  for (int j = 0; j < 4; j++) {
    int c = tid + j * 256;
    out[(long)row * DM + c] = (v[j] - mu) * inv * lnw[c] + lnb[c];
  }
}

// ---------------------------------------------------------------------------
extern "C" void kernel_launch(void* const* d_in, const int* in_sizes, int n_in,
                              void* d_out, int out_size, void* d_ws, size_t ws_size,
                              hipStream_t stream)
{
  const float* x         = (const float*)d_in[0];
  const float* fw_conv_w = (const float*)d_in[2];
  const float* fw_conv_b = (const float*)d_in[3];
  const float* fw_dt_b   = (const float*)d_in[6];
  const float* fw_Alog   = (const float*)d_in[7];
  const float* fw_Dp     = (const float*)d_in[8];
  const float* bw_conv_w = (const float*)d_in[11];
  const float* bw_conv_b = (const float*)d_in[12];
  const float* bw_dt_b   = (const float*)d_in[15];
  const float* bw_Alog   = (const float*)d_in[16];
  const float* bw_Dp     = (const float*)d_in[17];
  const float* proj_b    = (const float*)d_in[20];
  const float* ln_w      = (const float*)d_in[21];
  const float* ln_b      = (const float*)d_in[22];

  // workspace layout (peak ~65.3 MB):
  //   xz bf16 [2][1024][4096]  @ 0..16MB  (delta overwrites xi cols)
  //   u/g bf16 [2][1024][2048] @ 16..24MB (g in-place over u)
  //   xdbl bf16 [2][1024][96]  @ 24..24.4MB
  //   sumd f32 [2][64][2048]   @ 25..26MB
  //   hout bf16 [2][64][2048][16] @ 26..34MB
  //   wb bf16 (converted x + weights) @ 34..65.3MB
  //   phase 2 (over dead xz): fused bf16 [1024][2048] @0..4MB, fin f32 @4..8MB
  char* ws = (char*)d_ws;
  const size_t MB = 1024 * 1024;
  bf16*  xz    = (bf16*)(ws + 0);
  bf16*  u     = (bf16*)(ws + 16 * MB);
  bf16*  xdbl  = (bf16*)(ws + 24 * MB);
  float* sumd  = (float*)(ws + 25 * MB);
  bf16*  hout  = (bf16*)(ws + 26 * MB);
  bf16*  wb    = (bf16*)(ws + 34 * MB);
  bf16*  g     = u;
  bf16*  delta = xz;                      // xi columns, stride 4096
  bf16*  fused = (bf16*)(ws + 0);
  float* fin   = (float*)(ws + 4 * MB);

  bf16* xb     = wb + OFF_X;
  bf16* inw    = wb + OFF_INW;     // [2][4096][1024]
  bf16* xprojw = wb + OFF_XPROJ;   // [2][96][2048]
  bf16* dtw    = wb + OFF_DTW;     // [2][2048][64]
  bf16* outw   = wb + OFF_OUTW;    // [2][1024][2048]
  bf16* projw  = wb + OFF_PROJW;   // [1024][2048]

  dim3 blk(256);

  // 0. convert x + weights to bf16
  cvt_k<<<(CVT_TOTAL / 8 + 255) / 256, blk, 0, stream>>>(
      x, (const float*)d_in[1], (const float*)d_in[10],
      (const float*)d_in[4], (const float*)d_in[13],
      (const float*)d_in[5], (const float*)d_in[14],
      (const float*)d_in[9], (const float*)d_in[18],
      (const float*)d_in[19], wb);

  // 1. in-proj: xz[dir] = (flip?)xb @ in_w^T  (M=1024,N=4096,K=1024)
  gemm_bt<64,128><<<dim3(16, 32, 2), blk, 0, stream>>>(
      xb, inw, inw + 4194304L, (void*)xz, 1024, 4096, 1024, 1024, 1024, 4096,
      0L, (long)1024 * 4096, nullptr, nullptr, 1, 1, 0, nullptr, 0);

  // 2. depthwise conv + silu -> u
  conv_silu_k<<<2048, blk, 0, stream>>>(xz, fw_conv_w, bw_conv_w, fw_conv_b, bw_conv_b, u);

  // 3. x_dbl = u @ xproj_w^T   (N=96)
  gemm_bt<32,64><<<dim3(32, 2, 2), blk, 0, stream>>>(
      u, xprojw, xprojw + 196608L, (void*)xdbl, 1024, 96, 2048, 2048, 2048, 96,
      (long)1024 * 2048, (long)1024 * 96, nullptr, nullptr, 0, 1, 0, nullptr, 0);

  // 4. delta = softplus(dt @ dt_w^T + dt_b) -> xi cols of xz (ldc=4096)
  gemm_bt<64,128><<<dim3(16, 16, 2), blk, 0, stream>>>(
      xdbl, dtw, dtw + 131072L, (void*)delta, 1024, 2048, 64, 96, 64, 4096,
      (long)1024 * 96, (long)1024 * 4096, fw_dt_b, bw_dt_b, 0, 1, 1, nullptr, 0);

  // 5. chunk-parallel scan: p1 local -> p2 combine -> p3 rescan+gate
  scan_p1<<<dim3(8, NC, 2), blk, 0, stream>>>(xz, u, xdbl, fw_Alog, bw_Alog, hout, sumd);
  scan_p2<<<dim3(256), blk, 0, stream>>>(fw_Alog, bw_Alog, hout, sumd);
  scan_p3<<<dim3(8, NC, 2), blk, 0, stream>>>(xz, u, xdbl, fw_Alog, bw_Alog,
                                              fw_Dp, bw_Dp, hout, g);

  // 6. out-proj + residual + unflip + concat -> fused (bf16 [1024][2048])
  gemm_bt<32,64><<<dim3(32, 16, 2), blk, 0, stream>>>(
      g, outw, outw + 2097152L, (void*)fused, 1024, 1024, 2048, 2048, 2048, 1024,
      (long)1024 * 2048, 0L, nullptr, nullptr, 0, 1, 0, x, 1);

  // 7. final proj: fin = fused @ proj_w^T (fp32 out)
  gemm_bt<32,64><<<dim3(32, 16, 1), blk, 0, stream>>>(
      fused, projw, projw, (void*)fin, 1024, 1024, 2048, 2048, 2048, 1024,
      0L, 0L, nullptr, nullptr, 0, 0, 0, nullptr, 0);

  // 8. +proj_b, LayerNorm -> d_out (fp32)
  ln_k<<<1024, blk, 0, stream>>>(fin, proj_b, ln_w, ln_b, (float*)d_out);
}

// Round 10
// 324.347 us; speedup vs baseline: 1.4700x; 1.0373x over previous
//
#include <hip/hip_runtime.h>

typedef __bf16 bf16;
typedef __bf16 bf16x8 __attribute__((ext_vector_type(8)));
typedef float  f32x4  __attribute__((ext_vector_type(4)));

#define L_SEQ 1024
#define DM    1024
#define DI    2048
#define DTR   64
#define DSTATE 16
#define XD    96   // DT_RANK + 2*D_STATE
#define NC    64   // scan chunks
#define CS    16   // steps per chunk

__device__ __forceinline__ float bf2f(bf16 v){ return (float)v; }
__device__ __forceinline__ bf16  f2bf(float v){ return (bf16)v; }

// async global->LDS, 16B per lane; LDS dest = wave-uniform base + lane*16
__device__ __forceinline__ void gl_lds16(const bf16* g, bf16* l) {
  __builtin_amdgcn_global_load_lds(
      (const __attribute__((address_space(1))) unsigned int*)g,
      (__attribute__((address_space(3))) unsigned int*)l, 16, 0, 0);
}

// converted-weights element offsets inside wb
#define OFF_X      0L
#define OFF_INW    1048576L            // [2] x 4194304
#define OFF_XPROJ  9437184L            // [2] x 196608
#define OFF_DTW    9830400L            // [2] x 131072
#define OFF_OUTW   10092544L           // [2] x 2097152
#define OFF_PROJW  14286848L           // 2097152
#define CVT_TOTAL  16384000L

// ---------------------------------------------------------------------------
// fp32 -> bf16 conversion of x + all GEMM weights into wb (16.384M elems)
// ---------------------------------------------------------------------------
__global__ __launch_bounds__(256) void cvt_k(
    const float* __restrict__ x,
    const float* __restrict__ inw0, const float* __restrict__ inw1,
    const float* __restrict__ xp0,  const float* __restrict__ xp1,
    const float* __restrict__ dt0,  const float* __restrict__ dt1,
    const float* __restrict__ ow0,  const float* __restrict__ ow1,
    const float* __restrict__ pw,   bf16* __restrict__ wb)
{
  long i = ((long)blockIdx.x * 256 + threadIdx.x) * 8;
  if (i >= CVT_TOTAL) return;
  const float* src; long off;
  if      (i < OFF_INW)                 { src = x;    off = i - OFF_X; }
  else if (i < OFF_INW + 4194304L)      { src = inw0; off = i - OFF_INW; }
  else if (i < OFF_XPROJ)               { src = inw1; off = i - (OFF_INW + 4194304L); }
  else if (i < OFF_XPROJ + 196608L)     { src = xp0;  off = i - OFF_XPROJ; }
  else if (i < OFF_DTW)                 { src = xp1;  off = i - (OFF_XPROJ + 196608L); }
  else if (i < OFF_DTW + 131072L)       { src = dt0;  off = i - OFF_DTW; }
  else if (i < OFF_OUTW)                { src = dt1;  off = i - (OFF_DTW + 131072L); }
  else if (i < OFF_OUTW + 2097152L)     { src = ow0;  off = i - OFF_OUTW; }
  else if (i < OFF_PROJW)               { src = ow1;  off = i - (OFF_OUTW + 2097152L); }
  else                                  { src = pw;   off = i - OFF_PROJW; }
  f32x4 v0 = *(const f32x4*)(src + off);
  f32x4 v1 = *(const f32x4*)(src + off + 4);
  bf16x8 t;
  #pragma unroll
  for (int q = 0; q < 4; q++) { t[q] = (bf16)v0[q]; t[4+q] = (bf16)v1[q]; }
  *(bf16x8*)(wb + i) = t;
}

// ---------------------------------------------------------------------------
// All-bf16 MFMA GEMM, B^T layout: C[m][n] = sum_k A[m][k] * B[n][k]
// Templated tile BMxBN (BK=64), 256 threads = 2x2 waves. global_load_lds
// staging, XOR-8 swizzle (conflict-free, verified R7/R8).
// splitN: columns >= splitN go to Cv2 (same ldc/cOffZ, col-splitN) -- used by
//   in-proj to write xi and z halves into separate dense buffers.
// fuseRes=1: epilogue writes fused[row][z*DM+gn] = v + xF[row][gn], bf16,
//   with row = (z ? M-1-gm : gm)  (residual + unflip + concat for out-proj)
// ---------------------------------------------------------------------------
template<int BM, int BN>
__global__ __launch_bounds__(256) void gemm_bt(
    const bf16* __restrict__ A, const bf16* __restrict__ B0, const bf16* __restrict__ B1,
    void* __restrict__ Cv, void* __restrict__ Cv2, int splitN,
    int M, int N, int K, int lda, int ldb, int ldc,
    long aOffZ, long cOffZ,
    const float* __restrict__ bias0, const float* __restrict__ bias1,
    int flipA1, int writeBf16, int act,
    const float* __restrict__ xF, int fuseRes)
{
  constexpr int WM = BM / 2, WN = BN / 2;
  constexpr int MI = WM / 16, NJ = WN / 16;
  constexpr int ACALLS = BM / 32;
  constexpr int BCALLS = BN / 32;

  const int tid  = threadIdx.x;
  const int z    = blockIdx.z;
  const bf16*  Bp   = z ? B1 : B0;
  const float* bias = z ? bias1 : bias0;
  const int flip = z ? flipA1 : 0;
  const int bm = blockIdx.x * BM;
  const int bn = blockIdx.y * BN;

  __shared__ bf16 As[BM * 64];
  __shared__ bf16 Bs[BN * 64];

  f32x4 acc[MI][NJ];
  #pragma unroll
  for (int i=0;i<MI;i++)
    #pragma unroll
    for (int j=0;j<NJ;j++) { acc[i][j][0]=0.f; acc[i][j][1]=0.f; acc[i][j][2]=0.f; acc[i][j][3]=0.f; }

  const int wave = tid >> 6;
  const int lane = tid & 63;
  const int wm = (wave >> 1) * WM;
  const int wn = (wave & 1) * WN;
  const int fr  = lane & 15;
  const int frx = fr & 7;
  const int kqc = lane >> 4;

  const bf16* aSrc[ACALLS];
  int aOff[ACALLS];
  #pragma unroll
  for (int t = 0; t < ACALLS; t++) {
    int s = (wave * ACALLS + t) * 64 + lane;
    int r = s >> 3;
    int j = (s & 7) ^ (r & 7);
    int ar = bm + r;
    int agr = flip ? (M - 1 - ar) : ar;
    aSrc[t] = A + (long)z * aOffZ + (long)agr * lda + j * 8;
    aOff[t] = (wave * ACALLS + t) * 512;
  }
  const bf16* bSrc[BCALLS];
  int bOff[BCALLS];
  #pragma unroll
  for (int t = 0; t < BCALLS; t++) {
    int s = (wave * BCALLS + t) * 64 + lane;
    int r = s >> 3;
    int j = (s & 7) ^ (r & 7);
    int br = bn + r; if (br > N - 1) br = N - 1;
    bSrc[t] = Bp + (long)br * ldb + j * 8;
    bOff[t] = (wave * BCALLS + t) * 512;
  }

  for (int k0 = 0; k0 < K; k0 += 64) {
    #pragma unroll
    for (int t = 0; t < ACALLS; t++) gl_lds16(aSrc[t] + k0, &As[aOff[t]]);
    #pragma unroll
    for (int t = 0; t < BCALLS; t++) gl_lds16(bSrc[t] + k0, &Bs[bOff[t]]);
    __syncthreads();

    #pragma unroll
    for (int ks8 = 0; ks8 < 8; ks8 += 4) {
      bf16x8 af[MI], bfr[NJ];
      #pragma unroll
      for (int i=0;i<MI;i++) {
        int row = wm + i*16 + fr;
        af[i]  = *(const bf16x8*)&As[(row * 8 + ((ks8 + kqc) ^ frx)) * 8];
      }
      #pragma unroll
      for (int j=0;j<NJ;j++) {
        int row = wn + j*16 + fr;
        bfr[j] = *(const bf16x8*)&Bs[(row * 8 + ((ks8 + kqc) ^ frx)) * 8];
      }
      #pragma unroll
      for (int i=0;i<MI;i++)
        #pragma unroll
        for (int j=0;j<NJ;j++)
          acc[i][j] = __builtin_amdgcn_mfma_f32_16x16x32_bf16(af[i], bfr[j], acc[i][j], 0, 0, 0);
    }
    __syncthreads();
  }

  const int rr = (lane >> 4) * 4;
  const int cc = lane & 15;
  #pragma unroll
  for (int i=0;i<MI;i++) {
    #pragma unroll
    for (int j=0;j<NJ;j++) {
      int gn = bn + wn + j*16 + cc;
      if (gn >= N) continue;
      float bv = bias ? bias[gn] : 0.f;
      #pragma unroll
      for (int r=0;r<4;r++) {
        int gm = bm + wm + i*16 + rr + r;
        float v = acc[i][j][r] + bv;
        if (fuseRes) {
          long row = z ? (long)(M - 1 - gm) : (long)gm;
          float o = v + xF[row * DM + gn];
          ((bf16*)Cv)[row * (2 * DM) + (long)z * DM + gn] = f2bf(o);
        } else {
          // cheap softplus: max(v,0) + log(1+exp(-|v|)) via fast intrinsics
          if (act == 1) v = fmaxf(v, 0.f) + __logf(1.f + __expf(-fabsf(v)));
          int gn2 = gn;
          void* Cp = Cv;
          if (gn >= splitN) { gn2 = gn - splitN; Cp = Cv2; }
          long idx = (long)z * cOffZ + (long)gm * ldc + gn2;
          if (writeBf16) ((bf16*)Cp)[idx] = f2bf(v);
          else           ((float*)Cp)[idx] = v;
        }
      }
    }
  }
}

// ---------------------------------------------------------------------------
// depthwise causal conv(4) + bias + silu : u[dir][l][d], 8 channels/thread
// reads dense xi buffer [dir][l][DI]
// ---------------------------------------------------------------------------
__global__ __launch_bounds__(256) void conv_silu_k(
    const bf16* __restrict__ xi, const float* __restrict__ cw0, const float* __restrict__ cw1,
    const float* __restrict__ cb0, const float* __restrict__ cb1, bf16* __restrict__ u)
{
  int gid = blockIdx.x * 256 + threadIdx.x;     // over 2*L*DI/8 = 524288
  int dir = gid >> 18;
  int rem = gid & ((1 << 18) - 1);
  int l = rem >> 8;
  int d0 = (rem & 255) * 8;
  const float* w = dir ? cw1 : cw0;
  const float* b = dir ? cb1 : cb0;
  const bf16* xid = xi + (long)dir * L_SEQ * DI;
  float acc[8];
  #pragma unroll
  for (int q = 0; q < 8; q++) acc[q] = b[d0 + q];
  #pragma unroll
  for (int j = 0; j < 4; j++) {
    int ll = l - 3 + j;
    if (ll < 0) continue;
    bf16x8 xv = *(const bf16x8*)(xid + (long)ll * DI + d0);
    #pragma unroll
    for (int q = 0; q < 8; q++) acc[q] += w[(d0 + q) * 4 + j] * bf2f(xv[q]);
  }
  bf16x8 o;
  #pragma unroll
  for (int q = 0; q < 8; q++) {
    float s = acc[q] / (1.f + __expf(-acc[q]));
    o[q] = f2bf(s);
  }
  *(bf16x8*)(u + (long)dir * L_SEQ * DI + (long)l * DI + d0) = o;
}

// ---------------------------------------------------------------------------
// Chunk-parallel selective scan, 3 kernels (XCD-coherence via launch bounds).
// NC=64 chunks of CS=16; whole-chunk register preload (R9, verified).
// delta/z/u all dense [dir][l][DI].
// ---------------------------------------------------------------------------
__global__ __launch_bounds__(256) void scan_p1(
    const bf16* __restrict__ delta, const bf16* __restrict__ u, const bf16* __restrict__ xdbl,
    const float* __restrict__ Alog0, const float* __restrict__ Alog1,
    bf16* __restrict__ hout, float* __restrict__ sumd)
{
  const int tid = threadIdx.x;
  const int c   = blockIdx.y;
  const int dir = blockIdx.z;
  const int d   = blockIdx.x * 256 + tid;
  const float* Alog = dir ? Alog1 : Alog0;
  const bf16* dl = delta + (long)dir * L_SEQ * DI;
  const bf16* ud = u     + (long)dir * L_SEQ * DI;
  const bf16* xd = xdbl  + (long)dir * L_SEQ * XD;
  const int l0 = c * CS;

  __shared__ float lb[CS][16];
  {
    int ll = tid >> 4, n = tid & 15;    // CS*16 = 256 = one elem/thread
    lb[ll][n] = bf2f(xd[(long)(l0 + ll) * XD + DTR + n]);
  }

  float dl_r[CS], uu_r[CS];
  #pragma unroll
  for (int s = 0; s < CS; s++) {
    dl_r[s] = bf2f(dl[(long)(l0 + s) * DI + d]);
    uu_r[s] = bf2f(ud[(long)(l0 + s) * DI + d]);
  }
  __syncthreads();

  float An[16], h[16];
  #pragma unroll
  for (int n = 0; n < 16; n++) { An[n] = -__expf(Alog[d * 16 + n]); h[n] = 0.f; }
  float sd = 0.f;

  #pragma unroll
  for (int ll = 0; ll < CS; ll++) {
    float dlt = dl_r[ll];
    sd += dlt;
    float du = dlt * uu_r[ll];
    #pragma unroll
    for (int n = 0; n < 16; n++) {
      float a = __expf(dlt * An[n]);
      h[n] = h[n] * a + du * lb[ll][n];
    }
  }

  bf16* hp = hout + (((long)dir * NC + c) * DI + d) * 16;
  bf16x8 o0, o1;
  #pragma unroll
  for (int n = 0; n < 8; n++) { o0[n] = f2bf(h[n]); o1[n] = f2bf(h[8 + n]); }
  *(bf16x8*)hp = o0;
  *(bf16x8*)(hp + 8) = o1;
  sumd[((long)dir * NC + c) * DI + d] = sd;
}

__global__ __launch_bounds__(256) void scan_p2(
    const float* __restrict__ Alog0, const float* __restrict__ Alog1,
    bf16* hout, const float* __restrict__ sumd)
{
  int g = blockIdx.x * 256 + threadIdx.x;   // 2*2048*16 = 65536
  int dir = g >> 15;
  int rem = g & 32767;
  int d = rem >> 4;
  int n = rem & 15;
  const float* Alog = dir ? Alog1 : Alog0;
  float An = -__expf(Alog[d * 16 + n]);
  float hs = 0.f;
  #pragma unroll 4
  for (int c = 0; c < NC; c++) {
    long base = ((long)dir * NC + c) * DI + d;
    float tmp = bf2f(hout[base * 16 + n]);
    float P = __expf(An * sumd[base]);
    hout[base * 16 + n] = f2bf(hs);   // h_start for chunk c
    hs = P * hs + tmp;
  }
}

__global__ __launch_bounds__(256) void scan_p3(
    const bf16* delta, const bf16* zb, const bf16* u, const bf16* __restrict__ xdbl,
    const float* __restrict__ Alog0, const float* __restrict__ Alog1,
    const float* __restrict__ Dp0, const float* __restrict__ Dp1,
    const bf16* __restrict__ hout, bf16* g)
{
  const int tid = threadIdx.x;
  const int c   = blockIdx.y;
  const int dir = blockIdx.z;
  const int d   = blockIdx.x * 256 + tid;
  const float* Alog = dir ? Alog1 : Alog0;
  const float* Dp   = dir ? Dp1 : Dp0;
  const bf16* dl = delta + (long)dir * L_SEQ * DI;
  const bf16* zd = zb    + (long)dir * L_SEQ * DI;
  const bf16* ud = u     + (long)dir * L_SEQ * DI;
  const bf16* xd = xdbl  + (long)dir * L_SEQ * XD;
  bf16* gd = g + (long)dir * L_SEQ * DI;
  const int l0 = c * CS;

  __shared__ float lb[CS][16];
  __shared__ float lc[CS][16];
  {
    int i = tid * 2;                   // CS*32 = 512, 2 consecutive/thread
    int ll = i >> 5, j = i & 31;       // j even
    const bf16* p = xd + (long)(l0 + ll) * XD + DTR + j;
    float v0 = bf2f(p[0]), v1 = bf2f(p[1]);
    if (j < 16) { lb[ll][j] = v0; lb[ll][j + 1] = v1; }
    else        { lc[ll][j - 16] = v0; lc[ll][j - 15] = v1; }
  }

  float dl_r[CS], uu_r[CS], zv_r[CS];
  #pragma unroll
  for (int s = 0; s < CS; s++) {
    dl_r[s] = bf2f(dl[(long)(l0 + s) * DI + d]);
    zv_r[s] = bf2f(zd[(long)(l0 + s) * DI + d]);
    uu_r[s] = bf2f(ud[(long)(l0 + s) * DI + d]);
  }
  const bf16* hp = hout + (((long)dir * NC + c) * DI + d) * 16;
  bf16x8 h0 = *(const bf16x8*)hp;
  bf16x8 h1 = *(const bf16x8*)(hp + 8);
  __syncthreads();

  float An[16], h[16];
  #pragma unroll
  for (int n = 0; n < 16; n++) {
    An[n] = -__expf(Alog[d * 16 + n]);
    h[n] = bf2f(n < 8 ? h0[n & 7] : h1[n & 7]);
  }
  const float Dpv = Dp[d];

  #pragma unroll
  for (int ll = 0; ll < CS; ll++) {
    float dlt = dl_r[ll];
    float du = dlt * uu_r[ll];
    float y = 0.f;
    #pragma unroll
    for (int n = 0; n < 16; n++) {
      float a = __expf(dlt * An[n]);
      h[n] = h[n] * a + du * lb[ll][n];
      y += h[n] * lc[ll][n];
    }
    y += uu_r[ll] * Dpv;
    float zv = zv_r[ll];
    float sz = zv / (1.f + __expf(-zv));
    gd[(long)(l0 + ll) * DI + d] = f2bf(y * sz);
  }
}

// ---------------------------------------------------------------------------
// +proj_b then LayerNorm over last dim (1024), write fp32 out
// ---------------------------------------------------------------------------
__global__ __launch_bounds__(256) void ln_k(
    const float* __restrict__ fin, const float* __restrict__ pb,
    const float* __restrict__ lnw, const float* __restrict__ lnb, float* __restrict__ out)
{
  int row = blockIdx.x;
  int tid = threadIdx.x;
  float v[4]; float s1 = 0.f, s2 = 0.f;
  #pragma unroll
  for (int j = 0; j < 4; j++) {
    int c = tid + j * 256;
    v[j] = fin[(long)row * DM + c] + pb[c];
    s1 += v[j]; s2 += v[j] * v[j];
  }
  #pragma unroll
  for (int off = 32; off; off >>= 1) { s1 += __shfl_down(s1, off); s2 += __shfl_down(s2, off); }
  __shared__ float red[8];
  int wave = tid >> 6, lane = tid & 63;
  if (lane == 0) { red[wave] = s1; red[4 + wave] = s2; }
  __syncthreads();
  float t1 = red[0] + red[1] + red[2] + red[3];
  float t2 = red[4] + red[5] + red[6] + red[7];
  float mu = t1 / DM;
  float var = t2 / DM - mu * mu;
  float inv = rsqrtf(var + 1e-5f);
  #pragma unroll
  for (int j = 0; j < 4; j++) {
    int c = tid + j * 256;
    out[(long)row * DM + c] = (v[j] - mu) * inv * lnw[c] + lnb[c];
  }
}

// ---------------------------------------------------------------------------
extern "C" void kernel_launch(void* const* d_in, const int* in_sizes, int n_in,
                              void* d_out, int out_size, void* d_ws, size_t ws_size,
                              hipStream_t stream)
{
  const float* x         = (const float*)d_in[0];
  const float* fw_conv_w = (const float*)d_in[2];
  const float* fw_conv_b = (const float*)d_in[3];
  const float* fw_dt_b   = (const float*)d_in[6];
  const float* fw_Alog   = (const float*)d_in[7];
  const float* fw_Dp     = (const float*)d_in[8];
  const float* bw_conv_w = (const float*)d_in[11];
  const float* bw_conv_b = (const float*)d_in[12];
  const float* bw_dt_b   = (const float*)d_in[15];
  const float* bw_Alog   = (const float*)d_in[16];
  const float* bw_Dp     = (const float*)d_in[17];
  const float* proj_b    = (const float*)d_in[20];
  const float* ln_w      = (const float*)d_in[21];
  const float* ln_b      = (const float*)d_in[22];

  // workspace layout (peak ~65.3 MB, same as R9):
  //   xi bf16 [2][1024][2048] @ 0..8MB   (delta overwrites in place after conv)
  //   zb bf16 [2][1024][2048] @ 8..16MB
  //   u/g bf16 [2][1024][2048] @ 16..24MB (g in-place over u)
  //   xdbl bf16 [2][1024][96] @ 24..24.4MB
  //   sumd f32 [2][64][2048]  @ 25..26MB
  //   hout bf16 [2][64][2048][16] @ 26..34MB
  //   wb bf16 (converted x + weights) @ 34..65.3MB
  //   phase 2 (over dead xi): fused bf16 [1024][2048] @0..4MB, fin f32 @4..8MB
  char* ws = (char*)d_ws;
  const size_t MB = 1024 * 1024;
  bf16*  xi    = (bf16*)(ws + 0);
  bf16*  zb    = (bf16*)(ws + 8 * MB);
  bf16*  u     = (bf16*)(ws + 16 * MB);
  bf16*  xdbl  = (bf16*)(ws + 24 * MB);
  float* sumd  = (float*)(ws + 25 * MB);
  bf16*  hout  = (bf16*)(ws + 26 * MB);
  bf16*  wb    = (bf16*)(ws + 34 * MB);
  bf16*  g     = u;
  bf16*  delta = xi;                      // dense, in place over dead xi
  bf16*  fused = (bf16*)(ws + 0);
  float* fin   = (float*)(ws + 4 * MB);

  bf16* xb     = wb + OFF_X;
  bf16* inw    = wb + OFF_INW;     // [2][4096][1024]
  bf16* xprojw = wb + OFF_XPROJ;   // [2][96][2048]
  bf16* dtw    = wb + OFF_DTW;     // [2][2048][64]
  bf16* outw   = wb + OFF_OUTW;    // [2][1024][2048]
  bf16* projw  = wb + OFF_PROJW;   // [1024][2048]

  dim3 blk(256);
  const int BIGN = 1 << 30;

  // 0. convert x + weights to bf16
  cvt_k<<<(CVT_TOTAL / 8 + 255) / 256, blk, 0, stream>>>(
      x, (const float*)d_in[1], (const float*)d_in[10],
      (const float*)d_in[4], (const float*)d_in[13],
      (const float*)d_in[5], (const float*)d_in[14],
      (const float*)d_in[9], (const float*)d_in[18],
      (const float*)d_in[19], wb);

  // 1. in-proj: [xi|z][dir] = (flip?)xb @ in_w^T, split-written dense
  gemm_bt<64,128><<<dim3(16, 32, 2), blk, 0, stream>>>(
      xb, inw, inw + 4194304L, (void*)xi, (void*)zb, 2048,
      1024, 4096, 1024, 1024, 1024, 2048,
      0L, (long)1024 * 2048, nullptr, nullptr, 1, 1, 0, nullptr, 0);

  // 2. depthwise conv + silu -> u
  conv_silu_k<<<2048, blk, 0, stream>>>(xi, fw_conv_w, bw_conv_w, fw_conv_b, bw_conv_b, u);

  // 3. x_dbl = u @ xproj_w^T   (N=96)
  gemm_bt<32,64><<<dim3(32, 2, 2), blk, 0, stream>>>(
      u, xprojw, xprojw + 196608L, (void*)xdbl, nullptr, BIGN,
      1024, 96, 2048, 2048, 2048, 96,
      (long)1024 * 2048, (long)1024 * 96, nullptr, nullptr, 0, 1, 0, nullptr, 0);

  // 4. delta = softplus(dt @ dt_w^T + dt_b) -> dense over dead xi (ldc=2048)
  gemm_bt<32,64><<<dim3(32, 32, 2), blk, 0, stream>>>(
      xdbl, dtw, dtw + 131072L, (void*)delta, nullptr, BIGN,
      1024, 2048, 64, 96, 64, 2048,
      (long)1024 * 96, (long)1024 * 2048, fw_dt_b, bw_dt_b, 0, 1, 1, nullptr, 0);

  // 5. chunk-parallel scan: p1 local -> p2 combine -> p3 rescan+gate
  scan_p1<<<dim3(8, NC, 2), blk, 0, stream>>>(delta, u, xdbl, fw_Alog, bw_Alog, hout, sumd);
  scan_p2<<<dim3(256), blk, 0, stream>>>(fw_Alog, bw_Alog, hout, sumd);
  scan_p3<<<dim3(8, NC, 2), blk, 0, stream>>>(delta, zb, u, xdbl, fw_Alog, bw_Alog,
                                              fw_Dp, bw_Dp, hout, g);

  // 6. out-proj + residual + unflip + concat -> fused (bf16 [1024][2048])
  gemm_bt<32,64><<<dim3(32, 16, 2), blk, 0, stream>>>(
      g, outw, outw + 2097152L, (void*)fused, nullptr, BIGN,
      1024, 1024, 2048, 2048, 2048, 1024,
      (long)1024 * 2048, 0L, nullptr, nullptr, 0, 1, 0, x, 1);

  // 7. final proj: fin = fused @ proj_w^T (fp32 out)
  gemm_bt<32,64><<<dim3(32, 16, 1), blk, 0, stream>>>(
      fused, projw, projw, (void*)fin, nullptr, BIGN,
      1024, 1024, 2048, 2048, 2048, 1024,
      0L, 0L, nullptr, nullptr, 0, 0, 0, nullptr, 0);

  // 8. +proj_b, LayerNorm -> d_out (fp32)
  ln_k<<<1024, blk, 0, stream>>>(fin, proj_b, ln_w, ln_b, (float*)d_out);
}